// Round 1
// baseline (4332.178 us; speedup 1.0000x reference)
//
#include <hip/hip_runtime.h>

#define LN_EPS 1e-5f

// ---------------- degree / scale ----------------
__global__ __launch_bounds__(256)
void count_deg(const int* __restrict__ src, const int* __restrict__ dst,
               int* __restrict__ degs, int* __restrict__ degd, int E) {
  int t = blockIdx.x * 256 + threadIdx.x;
  if (t < E) {
    atomicAdd(&degs[src[t]], 1);
    atomicAdd(&degd[dst[t]], 1);
  }
}

__global__ __launch_bounds__(256)
void make_rs(const int* __restrict__ degs, const int* __restrict__ degd,
             float* __restrict__ rs_out, float* __restrict__ rs_in, int N) {
  int t = blockIdx.x * 256 + threadIdx.x;
  if (t < N) {
    rs_out[t] = rsqrtf((float)max(degs[t], 1));
    rs_in[t]  = rsqrtf((float)max(degd[t], 1));
  }
}

// ---------------- edge scatter-add (128 features, float4 chunks) ----------------
// out[dst[e]] += x[src[e]] * rs_out[src[e]]
__global__ __launch_bounds__(256)
void scatter128(const int* __restrict__ src, const int* __restrict__ dst,
                const float* __restrict__ x, const float* __restrict__ rs_out,
                float* __restrict__ out, int E) {
  int tid = blockIdx.x * 256 + threadIdx.x;
  int e = tid >> 5;           // 32 threads per edge
  if (e >= E) return;
  int c = (tid & 31) << 2;    // 4 floats per thread
  int s = src[e], d = dst[e];
  float sc = rs_out[s];
  const float4 v = *reinterpret_cast<const float4*>(x + (size_t)s * 128 + c);
  float* o = out + (size_t)d * 128 + c;
  atomicAdd(o + 0, v.x * sc);
  atomicAdd(o + 1, v.y * sc);
  atomicAdd(o + 2, v.z * sc);
  atomicAdd(o + 3, v.w * sc);
}

// ---------------- generic fp32 GEMM: C = act(rowscale[m] * (A@W) + bias) [+resid] ----
// A: [M,K] row-major (lda), W: [K,ncols] row-major (ldw), tile 64x64, K multiple of 16.
// Columns covered = gridDim.y * 64 (always exact here).
template<bool RELU, bool RESID>
__global__ __launch_bounds__(256)
void gemm_rs(const float* __restrict__ A, int lda,
             const float* __restrict__ W, int ldw,
             const float* __restrict__ bias,
             const float* __restrict__ rowscale,
             const float* __restrict__ resid, int ldr,
             float* __restrict__ C, int ldc,
             int M, int K) {
  __shared__ float As[16][64];
  __shared__ float Bs[16][64];
  const int t = threadIdx.x;
  const int m0 = blockIdx.x * 64;
  const int n0 = blockIdx.y * 64;
  const int tx = t & 15, ty = t >> 4;
  float acc[4][4] = {};

  for (int k0 = 0; k0 < K; k0 += 16) {
#pragma unroll
    for (int i = 0; i < 4; ++i) {           // A tile 64x16
      int idx = t + i * 256;
      int r = idx >> 4, kk = idx & 15;
      int m = m0 + r;
      As[kk][r] = (m < M) ? A[(size_t)m * lda + k0 + kk] : 0.f;
    }
#pragma unroll
    for (int i = 0; i < 4; ++i) {           // B tile 16x64
      int idx = t + i * 256;
      int kk = idx >> 6, c = idx & 63;
      Bs[kk][c] = W[(size_t)(k0 + kk) * ldw + n0 + c];
    }
    __syncthreads();
#pragma unroll
    for (int kk = 0; kk < 16; ++kk) {
      float a[4], b[4];
#pragma unroll
      for (int i = 0; i < 4; ++i) a[i] = As[kk][ty * 4 + i];
#pragma unroll
      for (int j = 0; j < 4; ++j) b[j] = Bs[kk][tx * 4 + j];
#pragma unroll
      for (int i = 0; i < 4; ++i)
#pragma unroll
        for (int j = 0; j < 4; ++j)
          acc[i][j] = fmaf(a[i], b[j], acc[i][j]);
    }
    __syncthreads();
  }

#pragma unroll
  for (int i = 0; i < 4; ++i) {
    int m = m0 + ty * 4 + i;
    if (m >= M) continue;
    float rs = rowscale ? rowscale[m] : 1.f;
#pragma unroll
    for (int j = 0; j < 4; ++j) {
      int n = n0 + tx * 4 + j;
      float v = fmaf(acc[i][j], rs, bias[n]);
      if (RESID) v += resid[(size_t)m * ldr + n];
      if (RELU) v = fmaxf(v, 0.f);
      C[(size_t)m * ldc + n] = v;
    }
  }
}

// ---------------- LayerNorm(cat) + features residual, one wave per node ------------
__global__ __launch_bounds__(256)
void ln_resid(const float* __restrict__ cat, const float* __restrict__ feat,
              const float* __restrict__ g, const float* __restrict__ b,
              float* __restrict__ h, int N) {
  int n = blockIdx.x * 4 + (threadIdx.x >> 6);
  int lane = threadIdx.x & 63;
  if (n >= N) return;
  float v0 = cat[(size_t)n * 128 + lane];
  float v1 = cat[(size_t)n * 128 + 64 + lane];
  float s = v0 + v1;
#pragma unroll
  for (int o = 1; o < 64; o <<= 1) s += __shfl_xor(s, o, 64);
  float mu = s * (1.f / 128.f);
  float d0 = v0 - mu, d1 = v1 - mu;
  float vv = d0 * d0 + d1 * d1;
#pragma unroll
  for (int o = 1; o < 64; o <<= 1) vv += __shfl_xor(vv, o, 64);
  float rstd = rsqrtf(vv * (1.f / 128.f) + LN_EPS);
  h[(size_t)n * 128 + lane]      = feat[(size_t)n * 128 + lane]      + d0 * rstd * g[lane]      + b[lane];
  h[(size_t)n * 128 + 64 + lane] = feat[(size_t)n * 128 + 64 + lane] + d1 * rstd * g[64 + lane] + b[64 + lane];
}

extern "C" void kernel_launch(void* const* d_in, const int* in_sizes, int n_in,
                              void* d_out, int out_size, void* d_ws, size_t ws_size,
                              hipStream_t stream) {
  const float* features = (const float*)d_in[0];
  const int*   src      = (const int*)d_in[1];
  const int*   dst      = (const int*)d_in[2];
  const float* W1a = (const float*)d_in[3];  const float* b1a = (const float*)d_in[4];
  const float* W2a = (const float*)d_in[5];  const float* b2a = (const float*)d_in[6];
  const float* W1b = (const float*)d_in[7];  const float* b1b = (const float*)d_in[8];
  const float* W2b = (const float*)d_in[9];  const float* b2b = (const float*)d_in[10];
  const float* Wf1 = (const float*)d_in[11]; const float* bf1 = (const float*)d_in[12];
  const float* Wf2 = (const float*)d_in[13]; const float* bf2 = (const float*)d_in[14];
  const float* ln_g = (const float*)d_in[15];
  const float* ln_b = (const float*)d_in[16];

  const int N = in_sizes[0] / 128;
  const int E = in_sizes[1];
  float* out = (float*)d_out;

  // workspace carve-up
  size_t off = 0;
  char* wsb = (char*)d_ws;
  auto take = [&](size_t bytes) -> void* {
    void* p = wsb + off;
    off += (bytes + 255) & ~(size_t)255;
    return p;
  };
  int*   deg_s  = (int*)  take((size_t)N * 4);
  int*   deg_d  = (int*)  take((size_t)N * 4);
  float* rs_out = (float*)take((size_t)N * 4);
  float* rs_in  = (float*)take((size_t)N * 4);
  float* A = (float*)take((size_t)N * 128 * 4);  // agg_shared, later h
  float* B = (float*)take((size_t)N * 128 * 4);  // h1a/h1b, later ffh
  float* C = (float*)take((size_t)N * 128 * 4);  // agg2a/agg2b
  float* D = (float*)take((size_t)N * 128 * 4);  // cat = [ha|hb]

  const int scatterBlocks = (int)(((size_t)E * 32 + 255) / 256);
  dim3 g128((N + 63) / 64, 2);
  dim3 g64((N + 63) / 64, 1);

  // degrees + scales
  hipMemsetAsync(deg_s, 0, (size_t)N * 4, stream);
  hipMemsetAsync(deg_d, 0, (size_t)N * 4, stream);
  count_deg<<<(E + 255) / 256, 256, 0, stream>>>(src, dst, deg_s, deg_d, E);
  make_rs<<<(N + 255) / 256, 256, 0, stream>>>(deg_s, deg_d, rs_out, rs_in, N);

  // shared first-layer aggregation
  hipMemsetAsync(A, 0, (size_t)N * 128 * 4, stream);
  scatter128<<<scatterBlocks, 256, 0, stream>>>(src, dst, features, rs_out, A, E);

  // ---- branch a ----
  gemm_rs<true, false><<<g128, 256, 0, stream>>>(A, 128, W1a, 128, b1a, rs_in, nullptr, 0, B, 128, N, 128);
  hipMemsetAsync(C, 0, (size_t)N * 128 * 4, stream);
  scatter128<<<scatterBlocks, 256, 0, stream>>>(src, dst, B, rs_out, C, E);
  gemm_rs<false, false><<<g64, 256, 0, stream>>>(C, 128, W2a, 64, b2a, rs_in, nullptr, 0, D, 128, N, 128);

  // ---- branch b ----
  gemm_rs<true, false><<<g128, 256, 0, stream>>>(A, 128, W1b, 128, b1b, rs_in, nullptr, 0, B, 128, N, 128);
  hipMemsetAsync(C, 0, (size_t)N * 128 * 4, stream);
  scatter128<<<scatterBlocks, 256, 0, stream>>>(src, dst, B, rs_out, C, E);
  gemm_rs<false, false><<<g64, 256, 0, stream>>>(C, 128, W2b, 64, b2b, rs_in, nullptr, 0, D + 64, 128, N, 128);

  // h = features + LN(cat)   (h -> A, which is free now)
  ln_resid<<<(N + 3) / 4, 256, 0, stream>>>(D, features, ln_g, ln_b, A, N);

  // ff = relu(h@Wf1+bf1)@Wf2+bf2 ; out = h + ff
  gemm_rs<true, false><<<g128, 256, 0, stream>>>(A, 128, Wf1, 128, bf1, nullptr, nullptr, 0, B, 128, N, 128);
  gemm_rs<false, true><<<g128, 256, 0, stream>>>(B, 128, Wf2, 128, bf2, nullptr, A, 128, out, 128, N, 128);
}

// Round 2
// 523.860 us; speedup vs baseline: 8.2697x; 8.2697x over previous
//
#include <hip/hip_runtime.h>

#define LN_EPS 1e-5f

// ---------------- degree count ----------------
__global__ __launch_bounds__(256)
void count_deg(const int* __restrict__ src, const int* __restrict__ dst,
               int* __restrict__ degs, int* __restrict__ degd, int E) {
  int t = blockIdx.x * 256 + threadIdx.x;
  if (t < E) {
    atomicAdd(&degs[src[t]], 1);
    atomicAdd(&degd[dst[t]], 1);
  }
}

__global__ __launch_bounds__(256)
void make_rs(const int* __restrict__ degs, const int* __restrict__ degd,
             float* __restrict__ rs_out, float* __restrict__ rs_in, int N) {
  int t = blockIdx.x * 256 + threadIdx.x;
  if (t < N) {
    rs_out[t] = rsqrtf((float)max(degs[t], 1));
    rs_in[t]  = rsqrtf((float)max(degd[t], 1));
  }
}

// ---------------- exclusive prefix scan (3-kernel, 1024 elems/block) ----------------
__global__ __launch_bounds__(256)
void scan_partial(const int* __restrict__ deg, int* __restrict__ part, int N) {
  __shared__ int sd[256];
  int base = blockIdx.x * 1024;
  int t = threadIdx.x;
  int s = 0;
#pragma unroll
  for (int i = 0; i < 4; ++i) { int idx = base + t * 4 + i; if (idx < N) s += deg[idx]; }
  sd[t] = s; __syncthreads();
  for (int o = 128; o > 0; o >>= 1) { if (t < o) sd[t] += sd[t + o]; __syncthreads(); }
  if (t == 0) part[blockIdx.x] = sd[0];
}

__global__ __launch_bounds__(256)
void scan_small(int* __restrict__ part, int nb) {
  __shared__ int sd[256];
  int t = threadIdx.x;
  int orig = (t < nb) ? part[t] : 0;
  sd[t] = orig; __syncthreads();
  for (int o = 1; o < 256; o <<= 1) {
    int v = (t >= o) ? sd[t - o] : 0;
    __syncthreads();
    sd[t] += v;
    __syncthreads();
  }
  if (t < nb) part[t] = sd[t] - orig;   // exclusive
}

__global__ __launch_bounds__(256)
void scan_final(const int* __restrict__ deg, const int* __restrict__ part,
                int* __restrict__ row_off, int N) {
  __shared__ int sd[256];
  int base = blockIdx.x * 1024;
  int t = threadIdx.x;
  int loc[4]; int s = 0;
#pragma unroll
  for (int i = 0; i < 4; ++i) {
    int idx = base + t * 4 + i;
    loc[i] = (idx < N) ? deg[idx] : 0;
    s += loc[i];
  }
  sd[t] = s; __syncthreads();
  for (int o = 1; o < 256; o <<= 1) {
    int v = (t >= o) ? sd[t - o] : 0;
    __syncthreads();
    sd[t] += v;
    __syncthreads();
  }
  int excl = sd[t] - s + part[blockIdx.x];
#pragma unroll
  for (int i = 0; i < 4; ++i) {
    int idx = base + t * 4 + i;
    if (idx < N) row_off[idx] = excl;
    excl += loc[i];
  }
  if (blockIdx.x == gridDim.x - 1 && t == 255) row_off[N] = excl;  // == E
}

__global__ __launch_bounds__(256)
void copy_i32(const int* __restrict__ a, int* __restrict__ b, int N) {
  int t = blockIdx.x * 256 + threadIdx.x;
  if (t < N) b[t] = a[t];
}

// ---------------- CSR fill (dst-bucketed source list) ----------------
__global__ __launch_bounds__(256)
void csr_fill(const int* __restrict__ src, const int* __restrict__ dst,
              int* __restrict__ cursor, int* __restrict__ csr_src, int E) {
  int e = blockIdx.x * 256 + threadIdx.x;
  if (e < E) {
    int p = atomicAdd(&cursor[dst[e]], 1);
    csr_src[p] = src[e];
  }
}

// ---------------- gather aggregation: out[n] = sum_{s in csr[n]} x[s]*rs_out[s] -----
// one wave per node, 2 floats per lane
__global__ __launch_bounds__(256)
void gather128(const int* __restrict__ row_off, const int* __restrict__ csr_src,
               const float* __restrict__ x, const float* __restrict__ rs_out,
               float* __restrict__ out, int N) {
  int n = blockIdx.x * 4 + (threadIdx.x >> 6);
  if (n >= N) return;
  int lane = threadIdx.x & 63;
  int beg = row_off[n], end = row_off[n + 1];
  float ax = 0.f, ay = 0.f;
  int k = beg;
  for (; k + 2 <= end; k += 2) {           // unroll-2 for load overlap
    int s0 = csr_src[k], s1 = csr_src[k + 1];
    float c0 = rs_out[s0], c1 = rs_out[s1];
    float2 v0 = *reinterpret_cast<const float2*>(x + (size_t)s0 * 128 + lane * 2);
    float2 v1 = *reinterpret_cast<const float2*>(x + (size_t)s1 * 128 + lane * 2);
    ax += v0.x * c0 + v1.x * c1;
    ay += v0.y * c0 + v1.y * c1;
  }
  if (k < end) {
    int s0 = csr_src[k];
    float c0 = rs_out[s0];
    float2 v0 = *reinterpret_cast<const float2*>(x + (size_t)s0 * 128 + lane * 2);
    ax += v0.x * c0;
    ay += v0.y * c0;
  }
  float2 r; r.x = ax; r.y = ay;
  *reinterpret_cast<float2*>(out + (size_t)n * 128 + lane * 2) = r;
}

// ---------------- generic fp32 GEMM: C = act(rowscale[m]*(A@W)+bias) [+resid] -------
template<bool RELU, bool RESID>
__global__ __launch_bounds__(256)
void gemm_rs(const float* __restrict__ A, int lda,
             const float* __restrict__ W, int ldw,
             const float* __restrict__ bias,
             const float* __restrict__ rowscale,
             const float* __restrict__ resid, int ldr,
             float* __restrict__ C, int ldc,
             int M, int K) {
  __shared__ float As[16][64];
  __shared__ float Bs[16][64];
  const int t = threadIdx.x;
  const int m0 = blockIdx.x * 64;
  const int n0 = blockIdx.y * 64;
  const int tx = t & 15, ty = t >> 4;
  float acc[4][4] = {};

  for (int k0 = 0; k0 < K; k0 += 16) {
#pragma unroll
    for (int i = 0; i < 4; ++i) {           // A tile 64x16
      int idx = t + i * 256;
      int r = idx >> 4, kk = idx & 15;
      int m = m0 + r;
      As[kk][r] = (m < M) ? A[(size_t)m * lda + k0 + kk] : 0.f;
    }
#pragma unroll
    for (int i = 0; i < 4; ++i) {           // B tile 16x64
      int idx = t + i * 256;
      int kk = idx >> 6, c = idx & 63;
      Bs[kk][c] = W[(size_t)(k0 + kk) * ldw + n0 + c];
    }
    __syncthreads();
#pragma unroll
    for (int kk = 0; kk < 16; ++kk) {
      float a[4], b[4];
#pragma unroll
      for (int i = 0; i < 4; ++i) a[i] = As[kk][ty * 4 + i];
#pragma unroll
      for (int j = 0; j < 4; ++j) b[j] = Bs[kk][tx * 4 + j];
#pragma unroll
      for (int i = 0; i < 4; ++i)
#pragma unroll
        for (int j = 0; j < 4; ++j)
          acc[i][j] = fmaf(a[i], b[j], acc[i][j]);
    }
    __syncthreads();
  }

#pragma unroll
  for (int i = 0; i < 4; ++i) {
    int m = m0 + ty * 4 + i;
    if (m >= M) continue;
    float rs = rowscale ? rowscale[m] : 1.f;
#pragma unroll
    for (int j = 0; j < 4; ++j) {
      int n = n0 + tx * 4 + j;
      float v = fmaf(acc[i][j], rs, bias[n]);
      if (RESID) v += resid[(size_t)m * ldr + n];
      if (RELU) v = fmaxf(v, 0.f);
      C[(size_t)m * ldc + n] = v;
    }
  }
}

// ---------------- LayerNorm(cat) + features residual, one wave per node ------------
__global__ __launch_bounds__(256)
void ln_resid(const float* __restrict__ cat, const float* __restrict__ feat,
              const float* __restrict__ g, const float* __restrict__ b,
              float* __restrict__ h, int N) {
  int n = blockIdx.x * 4 + (threadIdx.x >> 6);
  int lane = threadIdx.x & 63;
  if (n >= N) return;
  float v0 = cat[(size_t)n * 128 + lane];
  float v1 = cat[(size_t)n * 128 + 64 + lane];
  float s = v0 + v1;
#pragma unroll
  for (int o = 1; o < 64; o <<= 1) s += __shfl_xor(s, o, 64);
  float mu = s * (1.f / 128.f);
  float d0 = v0 - mu, d1 = v1 - mu;
  float vv = d0 * d0 + d1 * d1;
#pragma unroll
  for (int o = 1; o < 64; o <<= 1) vv += __shfl_xor(vv, o, 64);
  float rstd = rsqrtf(vv * (1.f / 128.f) + LN_EPS);
  h[(size_t)n * 128 + lane]      = feat[(size_t)n * 128 + lane]      + d0 * rstd * g[lane]      + b[lane];
  h[(size_t)n * 128 + 64 + lane] = feat[(size_t)n * 128 + 64 + lane] + d1 * rstd * g[64 + lane] + b[64 + lane];
}

extern "C" void kernel_launch(void* const* d_in, const int* in_sizes, int n_in,
                              void* d_out, int out_size, void* d_ws, size_t ws_size,
                              hipStream_t stream) {
  const float* features = (const float*)d_in[0];
  const int*   src      = (const int*)d_in[1];
  const int*   dst      = (const int*)d_in[2];
  const float* W1a = (const float*)d_in[3];  const float* b1a = (const float*)d_in[4];
  const float* W2a = (const float*)d_in[5];  const float* b2a = (const float*)d_in[6];
  const float* W1b = (const float*)d_in[7];  const float* b1b = (const float*)d_in[8];
  const float* W2b = (const float*)d_in[9];  const float* b2b = (const float*)d_in[10];
  const float* Wf1 = (const float*)d_in[11]; const float* bf1 = (const float*)d_in[12];
  const float* Wf2 = (const float*)d_in[13]; const float* bf2 = (const float*)d_in[14];
  const float* ln_g = (const float*)d_in[15];
  const float* ln_b = (const float*)d_in[16];

  const int N = in_sizes[0] / 128;
  const int E = in_sizes[1];
  float* out = (float*)d_out;

  // workspace carve-up
  size_t off = 0;
  char* wsb = (char*)d_ws;
  auto take = [&](size_t bytes) -> void* {
    void* p = wsb + off;
    off += (bytes + 255) & ~(size_t)255;
    return p;
  };
  int*   deg_s   = (int*)  take((size_t)N * 4);        // later reused as cursor
  int*   deg_d   = (int*)  take((size_t)N * 4);
  float* rs_out  = (float*)take((size_t)N * 4);
  float* rs_in   = (float*)take((size_t)N * 4);
  int*   row_off = (int*)  take((size_t)(N + 1) * 4);
  int*   part    = (int*)  take((size_t)256 * 4);
  int*   csr_src = (int*)  take((size_t)E * 4);
  float* A = (float*)take((size_t)N * 128 * 4);  // agg_shared, later h
  float* B = (float*)take((size_t)N * 128 * 4);  // h1a/h1b, later ffh
  float* C = (float*)take((size_t)N * 128 * 4);  // agg2a/agg2b
  float* D = (float*)take((size_t)N * 128 * 4);  // cat = [ha|hb]

  dim3 g128((N + 63) / 64, 2);
  dim3 g64((N + 63) / 64, 1);
  const int nScanBlocks = (N + 1023) / 1024;
  const int gatherBlocks = (N + 3) / 4;

  // degrees + scales
  hipMemsetAsync(deg_s, 0, (size_t)N * 4, stream);
  hipMemsetAsync(deg_d, 0, (size_t)N * 4, stream);
  count_deg<<<(E + 255) / 256, 256, 0, stream>>>(src, dst, deg_s, deg_d, E);
  make_rs<<<(N + 255) / 256, 256, 0, stream>>>(deg_s, deg_d, rs_out, rs_in, N);

  // CSR by dst: scan(deg_d) -> row_off; cursor (reuse deg_s) ; fill
  scan_partial<<<nScanBlocks, 256, 0, stream>>>(deg_d, part, N);
  scan_small<<<1, 256, 0, stream>>>(part, nScanBlocks);
  scan_final<<<nScanBlocks, 256, 0, stream>>>(deg_d, part, row_off, N);
  copy_i32<<<(N + 255) / 256, 256, 0, stream>>>(row_off, deg_s, N);
  csr_fill<<<(E + 255) / 256, 256, 0, stream>>>(src, dst, deg_s, csr_src, E);

  // shared first-layer aggregation (gather)
  gather128<<<gatherBlocks, 256, 0, stream>>>(row_off, csr_src, features, rs_out, A, N);

  // ---- branch a ----
  gemm_rs<true, false><<<g128, 256, 0, stream>>>(A, 128, W1a, 128, b1a, rs_in, nullptr, 0, B, 128, N, 128);
  gather128<<<gatherBlocks, 256, 0, stream>>>(row_off, csr_src, B, rs_out, C, N);
  gemm_rs<false, false><<<g64, 256, 0, stream>>>(C, 128, W2a, 64, b2a, rs_in, nullptr, 0, D, 128, N, 128);

  // ---- branch b ----
  gemm_rs<true, false><<<g128, 256, 0, stream>>>(A, 128, W1b, 128, b1b, rs_in, nullptr, 0, B, 128, N, 128);
  gather128<<<gatherBlocks, 256, 0, stream>>>(row_off, csr_src, B, rs_out, C, N);
  gemm_rs<false, false><<<g64, 256, 0, stream>>>(C, 128, W2b, 64, b2b, rs_in, nullptr, 0, D + 64, 128, N, 128);

  // h = features + LN(cat)   (h -> A, which is free now)
  ln_resid<<<(N + 3) / 4, 256, 0, stream>>>(D, features, ln_g, ln_b, A, N);

  // ff = relu(h@Wf1+bf1)@Wf2+bf2 ; out = h + ff
  gemm_rs<true, false><<<g128, 256, 0, stream>>>(A, 128, Wf1, 128, bf1, nullptr, nullptr, 0, B, 128, N, 128);
  gemm_rs<false, true><<<g128, 256, 0, stream>>>(B, 128, Wf2, 128, bf2, nullptr, A, 128, out, 128, N, 128);
}

// Round 3
// 523.179 us; speedup vs baseline: 8.2805x; 1.0013x over previous
//
#include <hip/hip_runtime.h>

#define LN_EPS 1e-5f

// ---------------- degree count ----------------
__global__ __launch_bounds__(256)
void count_deg(const int* __restrict__ src, const int* __restrict__ dst,
               int* __restrict__ degs, int* __restrict__ degd, int E) {
  int t = blockIdx.x * 256 + threadIdx.x;
  if (t < E) {
    atomicAdd(&degs[src[t]], 1);
    atomicAdd(&degd[dst[t]], 1);
  }
}

__global__ __launch_bounds__(256)
void make_rs(const int* __restrict__ degs, const int* __restrict__ degd,
             float* __restrict__ rs_out, float* __restrict__ rs_in, int N) {
  int t = blockIdx.x * 256 + threadIdx.x;
  if (t < N) {
    rs_out[t] = rsqrtf((float)max(degs[t], 1));
    rs_in[t]  = rsqrtf((float)max(degd[t], 1));
  }
}

// ---------------- exclusive prefix scan (3-kernel, 1024 elems/block) ----------------
__global__ __launch_bounds__(256)
void scan_partial(const int* __restrict__ deg, int* __restrict__ part, int N) {
  __shared__ int sd[256];
  int base = blockIdx.x * 1024;
  int t = threadIdx.x;
  int s = 0;
#pragma unroll
  for (int i = 0; i < 4; ++i) { int idx = base + t * 4 + i; if (idx < N) s += deg[idx]; }
  sd[t] = s; __syncthreads();
  for (int o = 128; o > 0; o >>= 1) { if (t < o) sd[t] += sd[t + o]; __syncthreads(); }
  if (t == 0) part[blockIdx.x] = sd[0];
}

__global__ __launch_bounds__(256)
void scan_small(int* __restrict__ part, int nb) {
  __shared__ int sd[256];
  int t = threadIdx.x;
  int orig = (t < nb) ? part[t] : 0;
  sd[t] = orig; __syncthreads();
  for (int o = 1; o < 256; o <<= 1) {
    int v = (t >= o) ? sd[t - o] : 0;
    __syncthreads();
    sd[t] += v;
    __syncthreads();
  }
  if (t < nb) part[t] = sd[t] - orig;   // exclusive
}

__global__ __launch_bounds__(256)
void scan_final(const int* __restrict__ deg, const int* __restrict__ part,
                int* __restrict__ row_off, int N) {
  __shared__ int sd[256];
  int base = blockIdx.x * 1024;
  int t = threadIdx.x;
  int loc[4]; int s = 0;
#pragma unroll
  for (int i = 0; i < 4; ++i) {
    int idx = base + t * 4 + i;
    loc[i] = (idx < N) ? deg[idx] : 0;
    s += loc[i];
  }
  sd[t] = s; __syncthreads();
  for (int o = 1; o < 256; o <<= 1) {
    int v = (t >= o) ? sd[t - o] : 0;
    __syncthreads();
    sd[t] += v;
    __syncthreads();
  }
  int excl = sd[t] - s + part[blockIdx.x];
#pragma unroll
  for (int i = 0; i < 4; ++i) {
    int idx = base + t * 4 + i;
    if (idx < N) row_off[idx] = excl;
    excl += loc[i];
  }
  if (blockIdx.x == gridDim.x - 1 && t == 255) row_off[N] = excl;  // == E
}

__global__ __launch_bounds__(256)
void copy_i32(const int* __restrict__ a, int* __restrict__ b, int N) {
  int t = blockIdx.x * 256 + threadIdx.x;
  if (t < N) b[t] = a[t];
}

// ---------------- CSR fill (dst-bucketed source list) ----------------
__global__ __launch_bounds__(256)
void csr_fill(const int* __restrict__ src, const int* __restrict__ dst,
              int* __restrict__ cursor, int* __restrict__ csr_src, int E) {
  int e = blockIdx.x * 256 + threadIdx.x;
  if (e < E) {
    int p = atomicAdd(&cursor[dst[e]], 1);
    csr_src[p] = src[e];
  }
}

// ---------------- gather 128-wide: out[n] = sum_s x[s]*rs_out[s], one wave/node ----
__global__ __launch_bounds__(256)
void gather128(const int* __restrict__ row_off, const int* __restrict__ csr_src,
               const float* __restrict__ x, const float* __restrict__ rs_out,
               float* __restrict__ out, int N) {
  int n = blockIdx.x * 4 + (threadIdx.x >> 6);
  if (n >= N) return;
  int lane = threadIdx.x & 63;
  int beg = row_off[n], end = row_off[n + 1];
  float ax = 0.f, ay = 0.f;
  int k = beg;
  for (; k + 2 <= end; k += 2) {
    int s0 = csr_src[k], s1 = csr_src[k + 1];
    float c0 = rs_out[s0], c1 = rs_out[s1];
    float2 v0 = *reinterpret_cast<const float2*>(x + (size_t)s0 * 128 + lane * 2);
    float2 v1 = *reinterpret_cast<const float2*>(x + (size_t)s1 * 128 + lane * 2);
    ax += v0.x * c0 + v1.x * c1;
    ay += v0.y * c0 + v1.y * c1;
  }
  if (k < end) {
    int s0 = csr_src[k];
    float c0 = rs_out[s0];
    float2 v0 = *reinterpret_cast<const float2*>(x + (size_t)s0 * 128 + lane * 2);
    ax += v0.x * c0;
    ay += v0.y * c0;
  }
  float2 r; r.x = ax; r.y = ay;
  *reinterpret_cast<float2*>(out + (size_t)n * 128 + lane * 2) = r;
}

// ---------------- gather 256-wide (both branches' h1 in one CSR pass) --------------
__global__ __launch_bounds__(256)
void gather256(const int* __restrict__ row_off, const int* __restrict__ csr_src,
               const float* __restrict__ x, const float* __restrict__ rs_out,
               float* __restrict__ out, int N) {
  int n = blockIdx.x * 4 + (threadIdx.x >> 6);
  if (n >= N) return;
  int lane = threadIdx.x & 63;
  int beg = row_off[n], end = row_off[n + 1];
  float4 a = {0.f, 0.f, 0.f, 0.f};
  int k = beg;
  for (; k + 2 <= end; k += 2) {
    int s0 = csr_src[k], s1 = csr_src[k + 1];
    float c0 = rs_out[s0], c1 = rs_out[s1];
    float4 v0 = *reinterpret_cast<const float4*>(x + (size_t)s0 * 256 + lane * 4);
    float4 v1 = *reinterpret_cast<const float4*>(x + (size_t)s1 * 256 + lane * 4);
    a.x += v0.x * c0 + v1.x * c1;
    a.y += v0.y * c0 + v1.y * c1;
    a.z += v0.z * c0 + v1.z * c1;
    a.w += v0.w * c0 + v1.w * c1;
  }
  if (k < end) {
    int s0 = csr_src[k];
    float c0 = rs_out[s0];
    float4 v0 = *reinterpret_cast<const float4*>(x + (size_t)s0 * 256 + lane * 4);
    a.x += v0.x * c0; a.y += v0.y * c0; a.z += v0.z * c0; a.w += v0.w * c0;
  }
  *reinterpret_cast<float4*>(out + (size_t)n * 256 + lane * 4) = a;
}

// ---------------- gemm1 both branches: h1cat = relu(rs_in*(A@[W1a|W1b]) + [b1a|b1b])
// grid (ceil(M/64), 4): blockIdx.y 0,1 -> W1a cols 0/64 ; 2,3 -> W1b cols 0/64.
__global__ __launch_bounds__(256)
void gemm1ab(const float* __restrict__ A,
             const float* __restrict__ W1a, const float* __restrict__ b1a,
             const float* __restrict__ W1b, const float* __restrict__ b1b,
             const float* __restrict__ rs_in,
             float* __restrict__ C, int M) {
  __shared__ float As[16][64];
  __shared__ float Bs[16][64];
  const float* W    = (blockIdx.y < 2) ? W1a : W1b;
  const float* bias = (blockIdx.y < 2) ? b1a : b1b;
  const int wc0 = (blockIdx.y & 1) * 64;   // column offset within the 128-wide W
  const int cb  = blockIdx.y * 64;         // column offset in 256-wide output
  const int t = threadIdx.x;
  const int m0 = blockIdx.x * 64;
  const int tx = t & 15, ty = t >> 4;
  float acc[4][4] = {};

  for (int k0 = 0; k0 < 128; k0 += 16) {
#pragma unroll
    for (int i = 0; i < 4; ++i) {
      int idx = t + i * 256;
      int r = idx >> 4, kk = idx & 15;
      int m = m0 + r;
      As[kk][r] = (m < M) ? A[(size_t)m * 128 + k0 + kk] : 0.f;
    }
#pragma unroll
    for (int i = 0; i < 4; ++i) {
      int idx = t + i * 256;
      int kk = idx >> 6, c = idx & 63;
      Bs[kk][c] = W[(size_t)(k0 + kk) * 128 + wc0 + c];
    }
    __syncthreads();
#pragma unroll
    for (int kk = 0; kk < 16; ++kk) {
      float a[4], b[4];
#pragma unroll
      for (int i = 0; i < 4; ++i) a[i] = As[kk][ty * 4 + i];
#pragma unroll
      for (int j = 0; j < 4; ++j) b[j] = Bs[kk][tx * 4 + j];
#pragma unroll
      for (int i = 0; i < 4; ++i)
#pragma unroll
        for (int j = 0; j < 4; ++j)
          acc[i][j] = fmaf(a[i], b[j], acc[i][j]);
    }
    __syncthreads();
  }

#pragma unroll
  for (int i = 0; i < 4; ++i) {
    int m = m0 + ty * 4 + i;
    if (m >= M) continue;
    float rs = rs_in[m];
#pragma unroll
    for (int j = 0; j < 4; ++j) {
      float v = fmaf(acc[i][j], rs, bias[wc0 + tx * 4 + j]);
      C[(size_t)m * 256 + cb + tx * 4 + j] = fmaxf(v, 0.f);
    }
  }
}

// ---------------- fused tail: gemm2a|b -> LN+resid -> FFN1 -> FFN2 -> out ----------
// One 64-row tile per block, 256 threads. Row-local after agg2cat.
__global__ __launch_bounds__(256)
void fused_tail(const float* __restrict__ agg2,     // [N,256]
                const float* __restrict__ W2a, const float* __restrict__ b2a,
                const float* __restrict__ W2b, const float* __restrict__ b2b,
                const float* __restrict__ feat, const float* __restrict__ rs_in,
                const float* __restrict__ ln_g, const float* __restrict__ ln_b,
                const float* __restrict__ Wf1, const float* __restrict__ bf1,
                const float* __restrict__ Wf2, const float* __restrict__ bf2,
                float* __restrict__ out, int N) {
  __shared__ float As[16][64];
  __shared__ float Bs[16][128];
  __shared__ float cat[64][129];   // branch outputs; later reused for ffh
  __shared__ float hs[64][129];    // h = feat + LN(cat)
  const int t = threadIdx.x;
  const int m0 = blockIdx.x * 64;
  const int tx = t & 15, ty = t >> 4;

  // ---- phase 1: the two 64x64 branch GEMMs (K=128 each) ----
#pragma unroll
  for (int br = 0; br < 2; ++br) {
    const float* W    = br ? W2b : W2a;
    const float* bias = br ? b2b : b2a;
    const int kb = br * 128;
    float acc[4][4] = {};
    for (int k0 = 0; k0 < 128; k0 += 16) {
#pragma unroll
      for (int i = 0; i < 4; ++i) {
        int idx = t + i * 256;
        int r = idx >> 4, kk = idx & 15;
        int m = m0 + r;
        As[kk][r] = (m < N) ? agg2[(size_t)m * 256 + kb + k0 + kk] : 0.f;
      }
#pragma unroll
      for (int i = 0; i < 4; ++i) {
        int idx = t + i * 256;
        int kk = idx >> 6, c = idx & 63;
        Bs[kk][c] = W[(size_t)(k0 + kk) * 64 + c];
      }
      __syncthreads();
#pragma unroll
      for (int kk = 0; kk < 16; ++kk) {
        float a[4], b[4];
#pragma unroll
        for (int i = 0; i < 4; ++i) a[i] = As[kk][ty * 4 + i];
#pragma unroll
        for (int j = 0; j < 4; ++j) b[j] = Bs[kk][tx * 4 + j];
#pragma unroll
        for (int i = 0; i < 4; ++i)
#pragma unroll
          for (int j = 0; j < 4; ++j)
            acc[i][j] = fmaf(a[i], b[j], acc[i][j]);
      }
      __syncthreads();
    }
#pragma unroll
    for (int i = 0; i < 4; ++i) {
      int m = m0 + ty * 4 + i;
      float rs = (m < N) ? rs_in[m] : 0.f;
#pragma unroll
      for (int j = 0; j < 4; ++j)
        cat[ty * 4 + i][br * 64 + tx * 4 + j] = fmaf(acc[i][j], rs, bias[tx * 4 + j]);
    }
    __syncthreads();
  }

  // ---- phase 2: LN + features residual -> hs ----
  {
    int wave = t >> 6, lane = t & 63;
    for (int r = wave; r < 64; r += 4) {
      int m = m0 + r;
      float v0 = cat[r][lane], v1 = cat[r][64 + lane];
      float s = v0 + v1;
#pragma unroll
      for (int o = 1; o < 64; o <<= 1) s += __shfl_xor(s, o, 64);
      float mu = s * (1.f / 128.f);
      float d0 = v0 - mu, d1 = v1 - mu;
      float vv = d0 * d0 + d1 * d1;
#pragma unroll
      for (int o = 1; o < 64; o <<= 1) vv += __shfl_xor(vv, o, 64);
      float rstd = rsqrtf(vv * (1.f / 128.f) + LN_EPS);
      float h0 = 0.f, h1 = 0.f;
      if (m < N) {
        h0 = feat[(size_t)m * 128 + lane]      + d0 * rstd * ln_g[lane]      + ln_b[lane];
        h1 = feat[(size_t)m * 128 + 64 + lane] + d1 * rstd * ln_g[64 + lane] + ln_b[64 + lane];
      }
      hs[r][lane] = h0;
      hs[r][64 + lane] = h1;
    }
  }
  __syncthreads();

  // ---- phase 3: FFN1 ffh = relu(hs @ Wf1 + bf1) -> cat (reuse) ----
  {
    float acc[4][8] = {};
    for (int k0 = 0; k0 < 128; k0 += 16) {
#pragma unroll
      for (int i = 0; i < 8; ++i) {          // Bs: 16x128
        int idx = t + i * 256;
        int kk = idx >> 7, c = idx & 127;
        Bs[kk][c] = Wf1[(size_t)(k0 + kk) * 128 + c];
      }
      __syncthreads();
#pragma unroll
      for (int kk = 0; kk < 16; ++kk) {
        float a[4], b[8];
#pragma unroll
        for (int i = 0; i < 4; ++i) a[i] = hs[ty * 4 + i][k0 + kk];
#pragma unroll
        for (int j = 0; j < 8; ++j) b[j] = Bs[kk][tx * 8 + j];
#pragma unroll
        for (int i = 0; i < 4; ++i)
#pragma unroll
          for (int j = 0; j < 8; ++j)
            acc[i][j] = fmaf(a[i], b[j], acc[i][j]);
      }
      __syncthreads();
    }
#pragma unroll
    for (int i = 0; i < 4; ++i)
#pragma unroll
      for (int j = 0; j < 8; ++j)
        cat[ty * 4 + i][tx * 8 + j] = fmaxf(acc[i][j] + bf1[tx * 8 + j], 0.f);
  }
  __syncthreads();

  // ---- phase 4: FFN2 out = hs + cat @ Wf2 + bf2 ----
  {
    float acc[4][8] = {};
    for (int k0 = 0; k0 < 128; k0 += 16) {
#pragma unroll
      for (int i = 0; i < 8; ++i) {
        int idx = t + i * 256;
        int kk = idx >> 7, c = idx & 127;
        Bs[kk][c] = Wf2[(size_t)(k0 + kk) * 128 + c];
      }
      __syncthreads();
#pragma unroll
      for (int kk = 0; kk < 16; ++kk) {
        float a[4], b[8];
#pragma unroll
        for (int i = 0; i < 4; ++i) a[i] = cat[ty * 4 + i][k0 + kk];
#pragma unroll
        for (int j = 0; j < 8; ++j) b[j] = Bs[kk][tx * 8 + j];
#pragma unroll
        for (int i = 0; i < 4; ++i)
#pragma unroll
          for (int j = 0; j < 8; ++j)
            acc[i][j] = fmaf(a[i], b[j], acc[i][j]);
      }
      __syncthreads();
    }
#pragma unroll
    for (int i = 0; i < 4; ++i) {
      int m = m0 + ty * 4 + i;
      if (m >= N) continue;
#pragma unroll
      for (int j = 0; j < 8; ++j) {
        int n = tx * 8 + j;
        out[(size_t)m * 128 + n] = hs[ty * 4 + i][n] + acc[i][j] + bf2[n];
      }
    }
  }
}

extern "C" void kernel_launch(void* const* d_in, const int* in_sizes, int n_in,
                              void* d_out, int out_size, void* d_ws, size_t ws_size,
                              hipStream_t stream) {
  const float* features = (const float*)d_in[0];
  const int*   src      = (const int*)d_in[1];
  const int*   dst      = (const int*)d_in[2];
  const float* W1a = (const float*)d_in[3];  const float* b1a = (const float*)d_in[4];
  const float* W2a = (const float*)d_in[5];  const float* b2a = (const float*)d_in[6];
  const float* W1b = (const float*)d_in[7];  const float* b1b = (const float*)d_in[8];
  const float* W2b = (const float*)d_in[9];  const float* b2b = (const float*)d_in[10];
  const float* Wf1 = (const float*)d_in[11]; const float* bf1 = (const float*)d_in[12];
  const float* Wf2 = (const float*)d_in[13]; const float* bf2 = (const float*)d_in[14];
  const float* ln_g = (const float*)d_in[15];
  const float* ln_b = (const float*)d_in[16];

  const int N = in_sizes[0] / 128;
  const int E = in_sizes[1];
  float* out = (float*)d_out;

  // workspace carve-up  (~106 MB total, same footprint as R2)
  size_t off = 0;
  char* wsb = (char*)d_ws;
  auto take = [&](size_t bytes) -> void* {
    void* p = wsb + off;
    off += (bytes + 255) & ~(size_t)255;
    return p;
  };
  int*   deg_s   = (int*)  take((size_t)N * 4);        // later reused as cursor
  int*   deg_d   = (int*)  take((size_t)N * 4);
  float* rs_out  = (float*)take((size_t)N * 4);
  float* rs_in   = (float*)take((size_t)N * 4);
  int*   row_off = (int*)  take((size_t)(N + 1) * 4);
  int*   part    = (int*)  take((size_t)256 * 4);
  int*   csr_src = (int*)  take((size_t)E * 4);
  float* P1 = (float*)take((size_t)N * 256 * 4);  // agg (first half), later agg2cat
  float* P2 = (float*)take((size_t)N * 256 * 4);  // h1cat
  float* agg     = P1;   // [N,128] using first half of P1
  float* h1cat   = P2;   // [N,256]
  float* agg2cat = P1;   // [N,256] overwrites agg (dead by then)

  const int nScanBlocks = (N + 1023) / 1024;
  const int gatherBlocks = (N + 3) / 4;
  const int mtiles = (N + 63) / 64;

  // degrees + scales
  hipMemsetAsync(deg_s, 0, (size_t)N * 4, stream);
  hipMemsetAsync(deg_d, 0, (size_t)N * 4, stream);
  count_deg<<<(E + 255) / 256, 256, 0, stream>>>(src, dst, deg_s, deg_d, E);
  make_rs<<<(N + 255) / 256, 256, 0, stream>>>(deg_s, deg_d, rs_out, rs_in, N);

  // CSR by dst
  scan_partial<<<nScanBlocks, 256, 0, stream>>>(deg_d, part, N);
  scan_small<<<1, 256, 0, stream>>>(part, nScanBlocks);
  scan_final<<<nScanBlocks, 256, 0, stream>>>(deg_d, part, row_off, N);
  copy_i32<<<(N + 255) / 256, 256, 0, stream>>>(row_off, deg_s, N);
  csr_fill<<<(E + 255) / 256, 256, 0, stream>>>(src, dst, deg_s, csr_src, E);

  // shared first-layer aggregation (gather, 128-wide)
  gather128<<<gatherBlocks, 256, 0, stream>>>(row_off, csr_src, features, rs_out, agg, N);

  // h1cat = relu(rs_in*(agg@[W1a|W1b]) + bias)    [N,256]
  gemm1ab<<<dim3(mtiles, 4), 256, 0, stream>>>(agg, W1a, b1a, W1b, b1b, rs_in, h1cat, N);

  // second aggregation, both branches in one pass   [N,256]
  gather256<<<gatherBlocks, 256, 0, stream>>>(row_off, csr_src, h1cat, rs_out, agg2cat, N);

  // fused: gemm2a|b -> LN+resid -> FFN1 -> FFN2 -> out
  fused_tail<<<mtiles, 256, 0, stream>>>(agg2cat, W2a, b2a, W2b, b2b,
                                         features, rs_in, ln_g, ln_b,
                                         Wf1, bf1, Wf2, bf2, out, N);
}

// Round 4
// 368.499 us; speedup vs baseline: 11.7563x; 1.4198x over previous
//
#include <hip/hip_runtime.h>

#define LN_EPS 1e-5f

typedef __attribute__((ext_vector_type(8))) short bf16x8;   // 8 bf16 = 4 VGPR (MFMA A/B frag)
typedef __attribute__((ext_vector_type(4))) float f32x4;    // MFMA C/D frag

#define MFMA_B16(a, b, c) __builtin_amdgcn_mfma_f32_16x16x32_bf16((a), (b), (c), 0, 0, 0)

__device__ __forceinline__ float bflo(unsigned int u) {     // low bf16 of packed uint -> f32
  return __builtin_bit_cast(float, u << 16);
}
__device__ __forceinline__ float bfhi(unsigned int u) {     // high bf16 -> f32
  return __builtin_bit_cast(float, u & 0xffff0000u);
}
__device__ __forceinline__ unsigned short f2bf(float f) {   // f32 -> bf16 RNE
  unsigned int u = __builtin_bit_cast(unsigned int, f);
  u += 0x7fffu + ((u >> 16) & 1u);
  return (unsigned short)(u >> 16);
}

// ---------------- degree count ----------------
__global__ __launch_bounds__(256)
void count_deg(const int* __restrict__ src, const int* __restrict__ dst,
               int* __restrict__ degs, int* __restrict__ degd, int E) {
  int t = blockIdx.x * 256 + threadIdx.x;
  if (t < E) {
    atomicAdd(&degs[src[t]], 1);
    atomicAdd(&degd[dst[t]], 1);
  }
}

__global__ __launch_bounds__(256)
void make_rs(const int* __restrict__ degs, const int* __restrict__ degd,
             float* __restrict__ rs_out, float* __restrict__ rs_in, int N) {
  int t = blockIdx.x * 256 + threadIdx.x;
  if (t < N) {
    rs_out[t] = rsqrtf((float)max(degs[t], 1));
    rs_in[t]  = rsqrtf((float)max(degd[t], 1));
  }
}

// ---------------- exclusive prefix scan (3-kernel, 1024 elems/block) ----------------
__global__ __launch_bounds__(256)
void scan_partial(const int* __restrict__ deg, int* __restrict__ part, int N) {
  __shared__ int sd[256];
  int base = blockIdx.x * 1024;
  int t = threadIdx.x;
  int s = 0;
#pragma unroll
  for (int i = 0; i < 4; ++i) { int idx = base + t * 4 + i; if (idx < N) s += deg[idx]; }
  sd[t] = s; __syncthreads();
  for (int o = 128; o > 0; o >>= 1) { if (t < o) sd[t] += sd[t + o]; __syncthreads(); }
  if (t == 0) part[blockIdx.x] = sd[0];
}

__global__ __launch_bounds__(256)
void scan_small(int* __restrict__ part, int nb) {
  __shared__ int sd[256];
  int t = threadIdx.x;
  int orig = (t < nb) ? part[t] : 0;
  sd[t] = orig; __syncthreads();
  for (int o = 1; o < 256; o <<= 1) {
    int v = (t >= o) ? sd[t - o] : 0;
    __syncthreads();
    sd[t] += v;
    __syncthreads();
  }
  if (t < nb) part[t] = sd[t] - orig;   // exclusive
}

__global__ __launch_bounds__(256)
void scan_final(const int* __restrict__ deg, const int* __restrict__ part,
                int* __restrict__ row_off, int N) {
  __shared__ int sd[256];
  int base = blockIdx.x * 1024;
  int t = threadIdx.x;
  int loc[4]; int s = 0;
#pragma unroll
  for (int i = 0; i < 4; ++i) {
    int idx = base + t * 4 + i;
    loc[i] = (idx < N) ? deg[idx] : 0;
    s += loc[i];
  }
  sd[t] = s; __syncthreads();
  for (int o = 1; o < 256; o <<= 1) {
    int v = (t >= o) ? sd[t - o] : 0;
    __syncthreads();
    sd[t] += v;
    __syncthreads();
  }
  int excl = sd[t] - s + part[blockIdx.x];
#pragma unroll
  for (int i = 0; i < 4; ++i) {
    int idx = base + t * 4 + i;
    if (idx < N) row_off[idx] = excl;
    excl += loc[i];
  }
  if (blockIdx.x == gridDim.x - 1 && t == 255) row_off[N] = excl;
}

__global__ __launch_bounds__(256)
void copy_i32(const int* __restrict__ a, int* __restrict__ b, int N) {
  int t = blockIdx.x * 256 + threadIdx.x;
  if (t < N) b[t] = a[t];
}

// ---------------- CSR fill ----------------
__global__ __launch_bounds__(256)
void csr_fill(const int* __restrict__ src, const int* __restrict__ dst,
              int* __restrict__ cursor, int* __restrict__ csr_src, int E) {
  int e = blockIdx.x * 256 + threadIdx.x;
  if (e < E) {
    int p = atomicAdd(&cursor[dst[e]], 1);
    csr_src[p] = src[e];
  }
}

// ---------------- converts ----------------
__global__ __launch_bounds__(256)
void convert_feat(const float* __restrict__ x, unsigned short* __restrict__ xb, int n4) {
  int t = blockIdx.x * 256 + threadIdx.x;
  if (t < n4) {
    float4 v = reinterpret_cast<const float4*>(x)[t];
    ushort4 r;
    r.x = f2bf(v.x); r.y = f2bf(v.y); r.z = f2bf(v.z); r.w = f2bf(v.w);
    reinterpret_cast<ushort4*>(xb)[t] = r;
  }
}

// 6 weight matrices -> transposed bf16 [n][k] (K always 128)
__global__ __launch_bounds__(256)
void convert_weights(const float* __restrict__ W1a, const float* __restrict__ W1b,
                     const float* __restrict__ W2a, const float* __restrict__ W2b,
                     const float* __restrict__ Wf1, const float* __restrict__ Wf2,
                     unsigned short* __restrict__ w1aT, unsigned short* __restrict__ w1bT,
                     unsigned short* __restrict__ w2aT, unsigned short* __restrict__ w2bT,
                     unsigned short* __restrict__ wf1T, unsigned short* __restrict__ wf2T) {
  const float* S; unsigned short* D; int NC;
  switch (blockIdx.x) {
    case 0: S = W1a; D = w1aT; NC = 128; break;
    case 1: S = W1b; D = w1bT; NC = 128; break;
    case 2: S = W2a; D = w2aT; NC = 64;  break;
    case 3: S = W2b; D = w2bT; NC = 64;  break;
    case 4: S = Wf1; D = wf1T; NC = 128; break;
    default: S = Wf2; D = wf2T; NC = 128; break;
  }
  int total = 128 * NC;
  for (int i = threadIdx.x; i < total; i += 256) {
    int k = i / NC, n = i - k * NC;
    D[n * 128 + k] = f2bf(S[i]);
  }
}

// ---------------- gather 128-wide bf16: one wave per node ----------------
__global__ __launch_bounds__(256)
void gather128b(const int* __restrict__ row_off, const int* __restrict__ csr_src,
                const unsigned short* __restrict__ xb, const float* __restrict__ rs_out,
                unsigned short* __restrict__ ob, int N) {
  int n = blockIdx.x * 4 + (threadIdx.x >> 6);
  if (n >= N) return;
  int lane = threadIdx.x & 63;
  int beg = row_off[n], end = row_off[n + 1];
  float ax = 0.f, ay = 0.f;
  int k = beg;
  for (; k + 2 <= end; k += 2) {
    int s0 = csr_src[k], s1 = csr_src[k + 1];
    float c0 = rs_out[s0], c1 = rs_out[s1];
    unsigned int v0 = *reinterpret_cast<const unsigned int*>(xb + (size_t)s0 * 128 + lane * 2);
    unsigned int v1 = *reinterpret_cast<const unsigned int*>(xb + (size_t)s1 * 128 + lane * 2);
    ax += bflo(v0) * c0 + bflo(v1) * c1;
    ay += bfhi(v0) * c0 + bfhi(v1) * c1;
  }
  if (k < end) {
    int s0 = csr_src[k];
    float c0 = rs_out[s0];
    unsigned int v0 = *reinterpret_cast<const unsigned int*>(xb + (size_t)s0 * 128 + lane * 2);
    ax += bflo(v0) * c0;
    ay += bfhi(v0) * c0;
  }
  unsigned int r = (unsigned int)f2bf(ax) | ((unsigned int)f2bf(ay) << 16);
  *reinterpret_cast<unsigned int*>(ob + (size_t)n * 128 + lane * 2) = r;
}

// ---------------- gather 256-wide bf16 ----------------
__global__ __launch_bounds__(256)
void gather256b(const int* __restrict__ row_off, const int* __restrict__ csr_src,
                const unsigned short* __restrict__ xb, const float* __restrict__ rs_out,
                unsigned short* __restrict__ ob, int N) {
  int n = blockIdx.x * 4 + (threadIdx.x >> 6);
  if (n >= N) return;
  int lane = threadIdx.x & 63;
  int beg = row_off[n], end = row_off[n + 1];
  float a0 = 0.f, a1 = 0.f, a2 = 0.f, a3 = 0.f;
  int k = beg;
  for (; k + 2 <= end; k += 2) {
    int s0 = csr_src[k], s1 = csr_src[k + 1];
    float c0 = rs_out[s0], c1 = rs_out[s1];
    uint2 v0 = *reinterpret_cast<const uint2*>(xb + (size_t)s0 * 256 + lane * 4);
    uint2 v1 = *reinterpret_cast<const uint2*>(xb + (size_t)s1 * 256 + lane * 4);
    a0 += bflo(v0.x) * c0 + bflo(v1.x) * c1;
    a1 += bfhi(v0.x) * c0 + bfhi(v1.x) * c1;
    a2 += bflo(v0.y) * c0 + bflo(v1.y) * c1;
    a3 += bfhi(v0.y) * c0 + bfhi(v1.y) * c1;
  }
  if (k < end) {
    int s0 = csr_src[k];
    float c0 = rs_out[s0];
    uint2 v0 = *reinterpret_cast<const uint2*>(xb + (size_t)s0 * 256 + lane * 4);
    a0 += bflo(v0.x) * c0;
    a1 += bfhi(v0.x) * c0;
    a2 += bflo(v0.y) * c0;
    a3 += bfhi(v0.y) * c0;
  }
  uint2 r;
  r.x = (unsigned int)f2bf(a0) | ((unsigned int)f2bf(a1) << 16);
  r.y = (unsigned int)f2bf(a2) | ((unsigned int)f2bf(a3) << 16);
  *reinterpret_cast<uint2*>(ob + (size_t)n * 256 + lane * 4) = r;
}

// ---------------- gemm1 both branches, MFMA: h1cat = relu(rs_in*(agg@[W1a|W1b])+bias)
// A: aggb [N,128] bf16, B: w1aT/w1bT [128][128] bf16 (row = out col n, k contiguous).
// 64 rows/block, each wave 16 rows x 256 cols.
__global__ __launch_bounds__(256)
void gemm1ab_mfma(const unsigned short* __restrict__ aggb,
                  const unsigned short* __restrict__ w1aT, const float* __restrict__ b1a,
                  const unsigned short* __restrict__ w1bT, const float* __restrict__ b1b,
                  const float* __restrict__ rs_in,
                  unsigned short* __restrict__ h1cat, int N) {
  int t = threadIdx.x, wid = t >> 6, lane = t & 63;
  int m0 = blockIdx.x * 64;
  int rA = m0 + wid * 16 + (lane & 15);             // A-frag row
  const unsigned short* ap = aggb + (size_t)min(rA, N - 1) * 128 + (lane >> 4) * 8;
  bf16x8 A[4];
#pragma unroll
  for (int k = 0; k < 4; ++k) A[k] = *reinterpret_cast<const bf16x8*>(ap + k * 32);

  int rw0 = m0 + wid * 16 + (lane >> 4) * 4;        // C rows this lane owns
  float rs[4];
#pragma unroll
  for (int j = 0; j < 4; ++j) rs[j] = rs_in[min(rw0 + j, N - 1)];

#pragma unroll
  for (int half = 0; half < 2; ++half) {
    const unsigned short* wT = half ? w1bT : w1aT;
    const float* bias = half ? b1b : b1a;
#pragma unroll
    for (int c = 0; c < 8; ++c) {
      const unsigned short* bp = wT + (size_t)(c * 16 + (lane & 15)) * 128 + (lane >> 4) * 8;
      f32x4 acc = {0.f, 0.f, 0.f, 0.f};
#pragma unroll
      for (int k = 0; k < 4; ++k)
        acc = MFMA_B16(A[k], *reinterpret_cast<const bf16x8*>(bp + k * 32), acc);
      int nloc = c * 16 + (lane & 15);
      int n = half * 128 + nloc;
      float bv = bias[nloc];
#pragma unroll
      for (int j = 0; j < 4; ++j) {
        int m = rw0 + j;
        if (m < N) {
          float v = fmaxf(fmaf(acc[j], rs[j], bv), 0.f);
          h1cat[(size_t)m * 256 + n] = f2bf(v);
        }
      }
    }
  }
}

// ---------------- fused tail (MFMA): gemm2a|b -> LN+resid -> FFN1 -> FFN2 -> out ----
__global__ __launch_bounds__(256)
void fused_tail(const unsigned short* __restrict__ agg2,   // [N,256] bf16
                const unsigned short* __restrict__ w2aT, const float* __restrict__ b2a,
                const unsigned short* __restrict__ w2bT, const float* __restrict__ b2b,
                const float* __restrict__ feat, const float* __restrict__ rs_in,
                const float* __restrict__ ln_g, const float* __restrict__ ln_b,
                const unsigned short* __restrict__ wf1T, const float* __restrict__ bf1,
                const unsigned short* __restrict__ wf2T, const float* __restrict__ bf2,
                float* __restrict__ out, int N) {
  __shared__ float catf[64][130];          // cat f32, then hs f32 in-place
  __shared__ unsigned short hsb[64 * 128]; // hs bf16, XOR-swizzled rows
  __shared__ unsigned short ffb[64 * 128]; // ffh bf16, XOR-swizzled rows
  int t = threadIdx.x, wid = t >> 6, lane = t & 63;
  int m0 = blockIdx.x * 64;
  int rA = m0 + wid * 16 + (lane & 15);
  const unsigned short* ap = agg2 + (size_t)min(rA, N - 1) * 256 + (lane >> 4) * 8;
  int rl0 = wid * 16 + (lane >> 4) * 4;    // local C-row base
  float rs[4];
#pragma unroll
  for (int j = 0; j < 4; ++j) rs[j] = rs_in[min(m0 + rl0 + j, N - 1)];

  // ---- phase 1: branch GEMMs (K=128 each) -> catf ----
#pragma unroll
  for (int br = 0; br < 2; ++br) {
    bf16x8 A[4];
#pragma unroll
    for (int k = 0; k < 4; ++k)
      A[k] = *reinterpret_cast<const bf16x8*>(ap + br * 128 + k * 32);
    const unsigned short* wT = br ? w2bT : w2aT;
    const float* bias = br ? b2b : b2a;
#pragma unroll
    for (int c = 0; c < 4; ++c) {
      const unsigned short* bp = wT + (size_t)(c * 16 + (lane & 15)) * 128 + (lane >> 4) * 8;
      f32x4 acc = {0.f, 0.f, 0.f, 0.f};
#pragma unroll
      for (int k = 0; k < 4; ++k)
        acc = MFMA_B16(A[k], *reinterpret_cast<const bf16x8*>(bp + k * 32), acc);
      int n = c * 16 + (lane & 15);
      float bv = bias[n];
#pragma unroll
      for (int j = 0; j < 4; ++j)
        catf[rl0 + j][br * 64 + n] = fmaf(acc[j], rs[j], bv);
    }
  }
  __syncthreads();

  // ---- phase 2: LN + features residual; hs f32 in-place, hs bf16 swizzled ----
  for (int r = wid; r < 64; r += 4) {
    int mc = min(m0 + r, N - 1);
    float v0 = catf[r][lane], v1 = catf[r][64 + lane];
    float s = v0 + v1;
#pragma unroll
    for (int o = 1; o < 64; o <<= 1) s += __shfl_xor(s, o, 64);
    float mu = s * (1.f / 128.f);
    float d0 = v0 - mu, d1 = v1 - mu;
    float vv = d0 * d0 + d1 * d1;
#pragma unroll
    for (int o = 1; o < 64; o <<= 1) vv += __shfl_xor(vv, o, 64);
    float rstd = rsqrtf(vv * (1.f / 128.f) + LN_EPS);
    float h0 = feat[(size_t)mc * 128 + lane]      + d0 * rstd * ln_g[lane]      + ln_b[lane];
    float h1 = feat[(size_t)mc * 128 + 64 + lane] + d1 * rstd * ln_g[64 + lane] + ln_b[64 + lane];
    catf[r][lane] = h0;
    catf[r][64 + lane] = h1;
    int sw = (r & 7) << 3;
    hsb[r * 128 + (lane ^ sw)] = f2bf(h0);
    hsb[r * 128 + ((64 + lane) ^ sw)] = f2bf(h1);
  }
  __syncthreads();

  // ---- phase 3: FFN1 = relu(hs @ Wf1 + bf1) -> ffb (each wave self-contained rows) --
  {
    int rloc = wid * 16 + (lane & 15);
    int sw = (rloc & 7) << 3;
    bf16x8 A[4];
#pragma unroll
    for (int k = 0; k < 4; ++k)
      A[k] = *reinterpret_cast<const bf16x8*>(hsb + rloc * 128 + ((k * 32 + (lane >> 4) * 8) ^ sw));
#pragma unroll
    for (int c = 0; c < 8; ++c) {
      const unsigned short* bp = wf1T + (size_t)(c * 16 + (lane & 15)) * 128 + (lane >> 4) * 8;
      f32x4 acc = {0.f, 0.f, 0.f, 0.f};
#pragma unroll
      for (int k = 0; k < 4; ++k)
        acc = MFMA_B16(A[k], *reinterpret_cast<const bf16x8*>(bp + k * 32), acc);
      int n = c * 16 + (lane & 15);
      float bv = bf1[n];
#pragma unroll
      for (int j = 0; j < 4; ++j) {
        int r2 = rl0 + j;
        float v = fmaxf(acc[j] + bv, 0.f);
        ffb[r2 * 128 + (n ^ ((r2 & 7) << 3))] = f2bf(v);
      }
    }
  }
  // no barrier needed: each wave reads only rows it wrote (compiler inserts lgkmcnt)

  // ---- phase 4: FFN2 + residual -> out ----
  {
    int rloc = wid * 16 + (lane & 15);
    int sw = (rloc & 7) << 3;
    bf16x8 A[4];
#pragma unroll
    for (int k = 0; k < 4; ++k)
      A[k] = *reinterpret_cast<const bf16x8*>(ffb + rloc * 128 + ((k * 32 + (lane >> 4) * 8) ^ sw));
#pragma unroll
    for (int c = 0; c < 8; ++c) {
      const unsigned short* bp = wf2T + (size_t)(c * 16 + (lane & 15)) * 128 + (lane >> 4) * 8;
      f32x4 acc = {0.f, 0.f, 0.f, 0.f};
#pragma unroll
      for (int k = 0; k < 4; ++k)
        acc = MFMA_B16(A[k], *reinterpret_cast<const bf16x8*>(bp + k * 32), acc);
      int n = c * 16 + (lane & 15);
      float bv = bf2[n];
#pragma unroll
      for (int j = 0; j < 4; ++j) {
        int m = m0 + rl0 + j;
        if (m < N) out[(size_t)m * 128 + n] = catf[rl0 + j][n] + acc[j] + bv;
      }
    }
  }
}

extern "C" void kernel_launch(void* const* d_in, const int* in_sizes, int n_in,
                              void* d_out, int out_size, void* d_ws, size_t ws_size,
                              hipStream_t stream) {
  const float* features = (const float*)d_in[0];
  const int*   src      = (const int*)d_in[1];
  const int*   dst      = (const int*)d_in[2];
  const float* W1a = (const float*)d_in[3];  const float* b1a = (const float*)d_in[4];
  const float* W2a = (const float*)d_in[5];  const float* b2a = (const float*)d_in[6];
  const float* W1b = (const float*)d_in[7];  const float* b1b = (const float*)d_in[8];
  const float* W2b = (const float*)d_in[9];  const float* b2b = (const float*)d_in[10];
  const float* Wf1 = (const float*)d_in[11]; const float* bf1 = (const float*)d_in[12];
  const float* Wf2 = (const float*)d_in[13]; const float* bf2 = (const float*)d_in[14];
  const float* ln_g = (const float*)d_in[15];
  const float* ln_b = (const float*)d_in[16];

  const int N = in_sizes[0] / 128;
  const int E = in_sizes[1];
  float* out = (float*)d_out;

  size_t off = 0;
  char* wsb = (char*)d_ws;
  auto take = [&](size_t bytes) -> void* {
    void* p = wsb + off;
    off += (bytes + 255) & ~(size_t)255;
    return p;
  };
  int*   deg_s   = (int*)  take((size_t)N * 4);        // later reused as cursor
  int*   deg_d   = (int*)  take((size_t)N * 4);
  float* rs_out  = (float*)take((size_t)N * 4);
  float* rs_in   = (float*)take((size_t)N * 4);
  int*   row_off = (int*)  take((size_t)(N + 1) * 4);
  int*   part    = (int*)  take((size_t)256 * 4);
  int*   csr_src = (int*)  take((size_t)E * 4);
  unsigned short* featb = (unsigned short*)take((size_t)N * 128 * 2);
  unsigned short* aggb  = (unsigned short*)take((size_t)N * 128 * 2);
  unsigned short* h1cat = (unsigned short*)take((size_t)N * 256 * 2);
  unsigned short* agg2  = (unsigned short*)take((size_t)N * 256 * 2);
  unsigned short* w1aT  = (unsigned short*)take(128 * 128 * 2);
  unsigned short* w1bT  = (unsigned short*)take(128 * 128 * 2);
  unsigned short* w2aT  = (unsigned short*)take(64 * 128 * 2);
  unsigned short* w2bT  = (unsigned short*)take(64 * 128 * 2);
  unsigned short* wf1T  = (unsigned short*)take(128 * 128 * 2);
  unsigned short* wf2T  = (unsigned short*)take(128 * 128 * 2);

  const int nScanBlocks = (N + 1023) / 1024;
  const int gatherBlocks = (N + 3) / 4;
  const int mtiles = (N + 63) / 64;
  const int n4 = (N * 128) / 4;

  // degrees + scales
  hipMemsetAsync(deg_s, 0, (size_t)N * 4, stream);
  hipMemsetAsync(deg_d, 0, (size_t)N * 4, stream);
  count_deg<<<(E + 255) / 256, 256, 0, stream>>>(src, dst, deg_s, deg_d, E);
  make_rs<<<(N + 255) / 256, 256, 0, stream>>>(deg_s, deg_d, rs_out, rs_in, N);

  // converts (independent)
  convert_feat<<<(n4 + 255) / 256, 256, 0, stream>>>(features, featb, n4);
  convert_weights<<<6, 256, 0, stream>>>(W1a, W1b, W2a, W2b, Wf1, Wf2,
                                         w1aT, w1bT, w2aT, w2bT, wf1T, wf2T);

  // CSR by dst
  scan_partial<<<nScanBlocks, 256, 0, stream>>>(deg_d, part, N);
  scan_small<<<1, 256, 0, stream>>>(part, nScanBlocks);
  scan_final<<<nScanBlocks, 256, 0, stream>>>(deg_d, part, row_off, N);
  copy_i32<<<(N + 255) / 256, 256, 0, stream>>>(row_off, deg_s, N);
  csr_fill<<<(E + 255) / 256, 256, 0, stream>>>(src, dst, deg_s, csr_src, E);

  // first aggregation (bf16 in/out, fp32 accum)
  gather128b<<<gatherBlocks, 256, 0, stream>>>(row_off, csr_src, featb, rs_out, aggb, N);

  // h1cat = relu(rs_in*(agg@[W1a|W1b]) + bias)  [N,256] bf16
  gemm1ab_mfma<<<mtiles, 256, 0, stream>>>(aggb, w1aT, b1a, w1bT, b1b, rs_in, h1cat, N);

  // second aggregation, both branches  [N,256] bf16
  gather256b<<<gatherBlocks, 256, 0, stream>>>(row_off, csr_src, h1cat, rs_out, agg2, N);

  // fused MFMA tail
  fused_tail<<<mtiles, 256, 0, stream>>>(agg2, w2aT, b2a, w2bT, b2b,
                                         features, rs_in, ln_g, ln_b,
                                         wf1T, bf1, wf2T, bf2, out, N);
}

// Round 5
// 342.865 us; speedup vs baseline: 12.6352x; 1.0748x over previous
//
#include <hip/hip_runtime.h>

#define LN_EPS 1e-5f

typedef __attribute__((ext_vector_type(8))) short bf16x8;   // 8 bf16 = 4 VGPR (MFMA A/B frag)
typedef __attribute__((ext_vector_type(4))) float f32x4;    // MFMA C/D frag

#define MFMA_B16(a, b, c) __builtin_amdgcn_mfma_f32_16x16x32_bf16((a), (b), (c), 0, 0, 0)

__device__ __forceinline__ float bflo(unsigned int u) {
  return __builtin_bit_cast(float, u << 16);
}
__device__ __forceinline__ float bfhi(unsigned int u) {
  return __builtin_bit_cast(float, u & 0xffff0000u);
}
__device__ __forceinline__ unsigned short f2bf(float f) {   // f32 -> bf16 RNE
  unsigned int u = __builtin_bit_cast(unsigned int, f);
  u += 0x7fffu + ((u >> 16) & 1u);
  return (unsigned short)(u >> 16);
}

// ---------------- degree count ----------------
__global__ __launch_bounds__(256)
void count_deg(const int* __restrict__ src, const int* __restrict__ dst,
               int* __restrict__ degs, int* __restrict__ degd, int E) {
  int t = blockIdx.x * 256 + threadIdx.x;
  if (t < E) {
    atomicAdd(&degs[src[t]], 1);
    atomicAdd(&degd[dst[t]], 1);
  }
}

__global__ __launch_bounds__(256)
void make_rs(const int* __restrict__ degs, const int* __restrict__ degd,
             float* __restrict__ rs_out, float* __restrict__ rs_in, int N) {
  int t = blockIdx.x * 256 + threadIdx.x;
  if (t < N) {
    rs_out[t] = rsqrtf((float)max(degs[t], 1));
    rs_in[t]  = rsqrtf((float)max(degd[t], 1));
  }
}

// ---------------- exclusive prefix scan ----------------
__global__ __launch_bounds__(256)
void scan_partial(const int* __restrict__ deg, int* __restrict__ part, int N) {
  __shared__ int sd[256];
  int base = blockIdx.x * 1024;
  int t = threadIdx.x;
  int s = 0;
#pragma unroll
  for (int i = 0; i < 4; ++i) { int idx = base + t * 4 + i; if (idx < N) s += deg[idx]; }
  sd[t] = s; __syncthreads();
  for (int o = 128; o > 0; o >>= 1) { if (t < o) sd[t] += sd[t + o]; __syncthreads(); }
  if (t == 0) part[blockIdx.x] = sd[0];
}

__global__ __launch_bounds__(256)
void scan_small(int* __restrict__ part, int nb) {
  __shared__ int sd[256];
  int t = threadIdx.x;
  int orig = (t < nb) ? part[t] : 0;
  sd[t] = orig; __syncthreads();
  for (int o = 1; o < 256; o <<= 1) {
    int v = (t >= o) ? sd[t - o] : 0;
    __syncthreads();
    sd[t] += v;
    __syncthreads();
  }
  if (t < nb) part[t] = sd[t] - orig;   // exclusive
}

__global__ __launch_bounds__(256)
void scan_final(const int* __restrict__ deg, const int* __restrict__ part,
                int* __restrict__ row_off, int* __restrict__ cursor, int N) {
  __shared__ int sd[256];
  int base = blockIdx.x * 1024;
  int t = threadIdx.x;
  int loc[4]; int s = 0;
#pragma unroll
  for (int i = 0; i < 4; ++i) {
    int idx = base + t * 4 + i;
    loc[i] = (idx < N) ? deg[idx] : 0;
    s += loc[i];
  }
  sd[t] = s; __syncthreads();
  for (int o = 1; o < 256; o <<= 1) {
    int v = (t >= o) ? sd[t - o] : 0;
    __syncthreads();
    sd[t] += v;
    __syncthreads();
  }
  int excl = sd[t] - s + part[blockIdx.x];
#pragma unroll
  for (int i = 0; i < 4; ++i) {
    int idx = base + t * 4 + i;
    if (idx < N) { row_off[idx] = excl; cursor[idx] = excl; }
    excl += loc[i];
  }
  if (blockIdx.x == gridDim.x - 1 && t == 255) row_off[N] = excl;
}

// ---------------- CSR fill ----------------
__global__ __launch_bounds__(256)
void csr_fill(const int* __restrict__ src, const int* __restrict__ dst,
              int* __restrict__ cursor, int* __restrict__ csr_src, int E) {
  int e = blockIdx.x * 256 + threadIdx.x;
  if (e < E) {
    int p = atomicAdd(&cursor[dst[e]], 1);
    csr_src[p] = src[e];
  }
}

// ---------------- converts ----------------
// featb[m] = bf16(features[m] * rs_out[m])  (pre-scaled so gather is a pure row-sum)
__global__ __launch_bounds__(256)
void convert_feat(const float* __restrict__ x, const float* __restrict__ rs_out,
                  unsigned short* __restrict__ xb, int n4) {
  int t = blockIdx.x * 256 + threadIdx.x;
  if (t < n4) {
    float sc = rs_out[t >> 5];          // 32 float4 per 128-wide row
    float4 v = reinterpret_cast<const float4*>(x)[t];
    ushort4 r;
    r.x = f2bf(v.x * sc); r.y = f2bf(v.y * sc); r.z = f2bf(v.z * sc); r.w = f2bf(v.w * sc);
    reinterpret_cast<ushort4*>(xb)[t] = r;
  }
}

// 6 weight matrices -> transposed bf16 [n][k] (K always 128)
__global__ __launch_bounds__(256)
void convert_weights(const float* __restrict__ W1a, const float* __restrict__ W1b,
                     const float* __restrict__ W2a, const float* __restrict__ W2b,
                     const float* __restrict__ Wf1, const float* __restrict__ Wf2,
                     unsigned short* __restrict__ w1aT, unsigned short* __restrict__ w1bT,
                     unsigned short* __restrict__ w2aT, unsigned short* __restrict__ w2bT,
                     unsigned short* __restrict__ wf1T, unsigned short* __restrict__ wf2T) {
  const float* S; unsigned short* D; int NC;
  switch (blockIdx.x) {
    case 0: S = W1a; D = w1aT; NC = 128; break;
    case 1: S = W1b; D = w1bT; NC = 128; break;
    case 2: S = W2a; D = w2aT; NC = 64;  break;
    case 3: S = W2b; D = w2bT; NC = 64;  break;
    case 4: S = Wf1; D = wf1T; NC = 128; break;
    default: S = Wf2; D = wf2T; NC = 128; break;
  }
  int total = 128 * NC;
  for (int i = threadIdx.x; i < total; i += 256) {
    int k = i / NC, n = i - k * NC;
    D[n * 128 + k] = f2bf(S[i]);
  }
}

// ---------------- gather 128-wide bf16 (pure row-sum, inputs pre-scaled) -----------
__global__ __launch_bounds__(256)
void gather128b(const int* __restrict__ row_off, const int* __restrict__ csr_src,
                const unsigned short* __restrict__ xb,
                unsigned short* __restrict__ ob, int N) {
  int n = blockIdx.x * 4 + (threadIdx.x >> 6);
  if (n >= N) return;
  int lane = threadIdx.x & 63;
  int beg = row_off[n], end = row_off[n + 1];
  float ax = 0.f, ay = 0.f;
  int k = beg;
  for (; k + 4 <= end; k += 4) {
    int s0 = csr_src[k], s1 = csr_src[k + 1], s2 = csr_src[k + 2], s3 = csr_src[k + 3];
    unsigned int v0 = *reinterpret_cast<const unsigned int*>(xb + (size_t)s0 * 128 + lane * 2);
    unsigned int v1 = *reinterpret_cast<const unsigned int*>(xb + (size_t)s1 * 128 + lane * 2);
    unsigned int v2 = *reinterpret_cast<const unsigned int*>(xb + (size_t)s2 * 128 + lane * 2);
    unsigned int v3 = *reinterpret_cast<const unsigned int*>(xb + (size_t)s3 * 128 + lane * 2);
    ax += bflo(v0) + bflo(v1) + bflo(v2) + bflo(v3);
    ay += bfhi(v0) + bfhi(v1) + bfhi(v2) + bfhi(v3);
  }
  for (; k < end; ++k) {
    int s0 = csr_src[k];
    unsigned int v0 = *reinterpret_cast<const unsigned int*>(xb + (size_t)s0 * 128 + lane * 2);
    ax += bflo(v0);
    ay += bfhi(v0);
  }
  unsigned int r = (unsigned int)f2bf(ax) | ((unsigned int)f2bf(ay) << 16);
  *reinterpret_cast<unsigned int*>(ob + (size_t)n * 128 + lane * 2) = r;
}

// ---------------- gather 256-wide bf16 (pure row-sum) ----------------
__global__ __launch_bounds__(256)
void gather256b(const int* __restrict__ row_off, const int* __restrict__ csr_src,
                const unsigned short* __restrict__ xb,
                unsigned short* __restrict__ ob, int N) {
  int n = blockIdx.x * 4 + (threadIdx.x >> 6);
  if (n >= N) return;
  int lane = threadIdx.x & 63;
  int beg = row_off[n], end = row_off[n + 1];
  float a0 = 0.f, a1 = 0.f, a2 = 0.f, a3 = 0.f;
  int k = beg;
  for (; k + 4 <= end; k += 4) {
    int s0 = csr_src[k], s1 = csr_src[k + 1], s2 = csr_src[k + 2], s3 = csr_src[k + 3];
    uint2 v0 = *reinterpret_cast<const uint2*>(xb + (size_t)s0 * 256 + lane * 4);
    uint2 v1 = *reinterpret_cast<const uint2*>(xb + (size_t)s1 * 256 + lane * 4);
    uint2 v2 = *reinterpret_cast<const uint2*>(xb + (size_t)s2 * 256 + lane * 4);
    uint2 v3 = *reinterpret_cast<const uint2*>(xb + (size_t)s3 * 256 + lane * 4);
    a0 += bflo(v0.x) + bflo(v1.x) + bflo(v2.x) + bflo(v3.x);
    a1 += bfhi(v0.x) + bfhi(v1.x) + bfhi(v2.x) + bfhi(v3.x);
    a2 += bflo(v0.y) + bflo(v1.y) + bflo(v2.y) + bflo(v3.y);
    a3 += bfhi(v0.y) + bfhi(v1.y) + bfhi(v2.y) + bfhi(v3.y);
  }
  for (; k < end; ++k) {
    int s0 = csr_src[k];
    uint2 v0 = *reinterpret_cast<const uint2*>(xb + (size_t)s0 * 256 + lane * 4);
    a0 += bflo(v0.x); a1 += bfhi(v0.x); a2 += bflo(v0.y); a3 += bfhi(v0.y);
  }
  uint2 r;
  r.x = (unsigned int)f2bf(a0) | ((unsigned int)f2bf(a1) << 16);
  r.y = (unsigned int)f2bf(a2) | ((unsigned int)f2bf(a3) << 16);
  *reinterpret_cast<uint2*>(ob + (size_t)n * 256 + lane * 4) = r;
}

// ---------------- gemm1 both branches, MFMA ---------------------------------------
// h1cat[m] = bf16( relu(rs_in[m]*(agg@[W1a|W1b]) + bias) * rs_out[m] )   (pre-scaled
// by rs_out so the second gather is a pure row-sum).
__global__ __launch_bounds__(256)
void gemm1ab_mfma(const unsigned short* __restrict__ aggb,
                  const unsigned short* __restrict__ w1aT, const float* __restrict__ b1a,
                  const unsigned short* __restrict__ w1bT, const float* __restrict__ b1b,
                  const float* __restrict__ rs_in, const float* __restrict__ rs_out,
                  unsigned short* __restrict__ h1cat, int N) {
  int t = threadIdx.x, wid = t >> 6, lane = t & 63;
  int m0 = blockIdx.x * 64;
  int ll = lane & 15, lg = lane >> 4;
  int rA = m0 + wid * 16 + ll;
  const unsigned short* ap = aggb + (size_t)min(rA, N - 1) * 128 + lg * 8;
  bf16x8 A[4];
#pragma unroll
  for (int k = 0; k < 4; ++k) A[k] = *reinterpret_cast<const bf16x8*>(ap + k * 32);

  int rw0 = m0 + wid * 16 + lg * 4;
  float rsi[4], rso[4];
#pragma unroll
  for (int j = 0; j < 4; ++j) {
    int m = min(rw0 + j, N - 1);
    rsi[j] = rs_in[m];
    rso[j] = rs_out[m];
  }

#pragma unroll
  for (int half = 0; half < 2; ++half) {
    const unsigned short* wT = half ? w1bT : w1aT;
    const float* bias = half ? b1b : b1a;
#pragma unroll
    for (int c = 0; c < 8; ++c) {
      const unsigned short* bp = wT + (size_t)(c * 16 + ll) * 128 + lg * 8;
      f32x4 acc = {0.f, 0.f, 0.f, 0.f};
#pragma unroll
      for (int k = 0; k < 4; ++k)
        acc = MFMA_B16(A[k], *reinterpret_cast<const bf16x8*>(bp + k * 32), acc);
      int nloc = c * 16 + ll;
      int n = half * 128 + nloc;
      float bv = bias[nloc];
#pragma unroll
      for (int j = 0; j < 4; ++j) {
        int m = rw0 + j;
        if (m < N) {
          float v = fmaxf(fmaf(acc[j], rsi[j], bv), 0.f) * rso[j];
          h1cat[(size_t)m * 256 + n] = f2bf(v);
        }
      }
    }
  }
}

// ---------------- fused tail: all wave-local, zero barriers ------------------------
// phase1 accs stay in regs; LN via 16-lane shfl_xor; h kept in regs for residual.
__global__ __launch_bounds__(256, 4)
void fused_tail(const unsigned short* __restrict__ agg2,   // [N,256] bf16
                const unsigned short* __restrict__ w2aT, const float* __restrict__ b2a,
                const unsigned short* __restrict__ w2bT, const float* __restrict__ b2b,
                const float* __restrict__ feat, const float* __restrict__ rs_in,
                const float* __restrict__ ln_g, const float* __restrict__ ln_b,
                const unsigned short* __restrict__ wf1T, const float* __restrict__ bf1,
                const unsigned short* __restrict__ wf2T, const float* __restrict__ bf2,
                float* __restrict__ out, int N) {
  __shared__ unsigned short hsb[64 * 128]; // hs bf16, XOR-swizzled; wave-private rows
  __shared__ unsigned short ffb[64 * 128]; // ffh bf16, XOR-swizzled; wave-private rows
  int t = threadIdx.x, wid = t >> 6, lane = t & 63;
  int m0 = blockIdx.x * 64;
  int ll = lane & 15, lg = lane >> 4;
  int rl0 = wid * 16 + lg * 4;             // local C-row base (this lane's 4 rows)

  // ---- phase 1: two branch GEMMs (K=128), accs in registers ----
  int rA = m0 + wid * 16 + ll;
  const unsigned short* ap = agg2 + (size_t)min(rA, N - 1) * 256 + lg * 8;
  f32x4 acc1[2][4];
#pragma unroll
  for (int br = 0; br < 2; ++br) {
    bf16x8 A[4];
#pragma unroll
    for (int k = 0; k < 4; ++k)
      A[k] = *reinterpret_cast<const bf16x8*>(ap + br * 128 + k * 32);
    const unsigned short* wT = br ? w2bT : w2aT;
#pragma unroll
    for (int c = 0; c < 4; ++c) {
      const unsigned short* bp = wT + (size_t)(c * 16 + ll) * 128 + lg * 8;
      f32x4 a = {0.f, 0.f, 0.f, 0.f};
#pragma unroll
      for (int k = 0; k < 4; ++k)
        a = MFMA_B16(A[k], *reinterpret_cast<const bf16x8*>(bp + k * 32), a);
      acc1[br][c] = a;
    }
  }

  // ---- phase 2: bias+rs, in-register LN over the 16-lane group, residual ----
  float x[8][4];                           // [col-tile ct: n=ct*16+ll][row j]; later h
  float s[4] = {0.f, 0.f, 0.f, 0.f}, q[4] = {0.f, 0.f, 0.f, 0.f};
#pragma unroll
  for (int br = 0; br < 2; ++br) {
    const float* bias = br ? b2b : b2a;
#pragma unroll
    for (int c = 0; c < 4; ++c) {
      float bv = bias[c * 16 + ll];
#pragma unroll
      for (int j = 0; j < 4; ++j) {
        int m = min(m0 + rl0 + j, N - 1);
        float v = fmaf(acc1[br][c][j], rs_in[m], bv);
        x[br * 4 + c][j] = v;
        s[j] += v;
        q[j] += v * v;
      }
    }
  }
#pragma unroll
  for (int o = 1; o < 16; o <<= 1) {
#pragma unroll
    for (int j = 0; j < 4; ++j) {
      s[j] += __shfl_xor(s[j], o, 64);
      q[j] += __shfl_xor(q[j], o, 64);
    }
  }
  float mu[4], rstd[4];
#pragma unroll
  for (int j = 0; j < 4; ++j) {
    mu[j] = s[j] * (1.f / 128.f);
    float var = fmaxf(q[j] * (1.f / 128.f) - mu[j] * mu[j], 0.f);
    rstd[j] = rsqrtf(var + LN_EPS);
  }
#pragma unroll
  for (int ct = 0; ct < 8; ++ct) {
    int n = ct * 16 + ll;
    float gv = ln_g[n], bv = ln_b[n];
#pragma unroll
    for (int j = 0; j < 4; ++j) {
      int m = min(m0 + rl0 + j, N - 1);
      float hv = feat[(size_t)m * 128 + n] + (x[ct][j] - mu[j]) * rstd[j] * gv + bv;
      x[ct][j] = hv;                                     // keep f32 h for residual
      int r = rl0 + j;
      hsb[r * 128 + (n ^ ((r & 7) << 3))] = f2bf(hv);    // swizzled bf16 for FFN1
    }
  }
  // no barrier: each wave reads only rows it wrote

  // ---- phase 3: FFN1 = relu(hs @ Wf1 + bf1) -> ffb ----
  {
    int rloc = wid * 16 + ll;
    int swr = (rloc & 7) << 3;
    bf16x8 A[4];
#pragma unroll
    for (int k = 0; k < 4; ++k)
      A[k] = *reinterpret_cast<const bf16x8*>(hsb + rloc * 128 + ((lg * 8 + k * 32) ^ swr));
#pragma unroll
    for (int c = 0; c < 8; ++c) {
      const unsigned short* bp = wf1T + (size_t)(c * 16 + ll) * 128 + lg * 8;
      f32x4 a = {0.f, 0.f, 0.f, 0.f};
#pragma unroll
      for (int k = 0; k < 4; ++k)
        a = MFMA_B16(A[k], *reinterpret_cast<const bf16x8*>(bp + k * 32), a);
      int n = c * 16 + ll;
      float bv = bf1[n];
#pragma unroll
      for (int j = 0; j < 4; ++j) {
        int r = rl0 + j;
        ffb[r * 128 + (n ^ ((r & 7) << 3))] = f2bf(fmaxf(a[j] + bv, 0.f));
      }
    }
  }

  // ---- phase 4: FFN2 + residual -> out ----
  {
    int rloc = wid * 16 + ll;
    int swr = (rloc & 7) << 3;
    bf16x8 A[4];
#pragma unroll
    for (int k = 0; k < 4; ++k)
      A[k] = *reinterpret_cast<const bf16x8*>(ffb + rloc * 128 + ((lg * 8 + k * 32) ^ swr));
#pragma unroll
    for (int c = 0; c < 8; ++c) {
      const unsigned short* bp = wf2T + (size_t)(c * 16 + ll) * 128 + lg * 8;
      f32x4 a = {0.f, 0.f, 0.f, 0.f};
#pragma unroll
      for (int k = 0; k < 4; ++k)
        a = MFMA_B16(A[k], *reinterpret_cast<const bf16x8*>(bp + k * 32), a);
      int n = c * 16 + ll;
      float bv = bf2[n];
#pragma unroll
      for (int j = 0; j < 4; ++j) {
        int m = m0 + rl0 + j;
        if (m < N) out[(size_t)m * 128 + n] = x[c][j] + a[j] + bv;
      }
    }
  }
}

extern "C" void kernel_launch(void* const* d_in, const int* in_sizes, int n_in,
                              void* d_out, int out_size, void* d_ws, size_t ws_size,
                              hipStream_t stream) {
  const float* features = (const float*)d_in[0];
  const int*   src      = (const int*)d_in[1];
  const int*   dst      = (const int*)d_in[2];
  const float* W1a = (const float*)d_in[3];  const float* b1a = (const float*)d_in[4];
  const float* W2a = (const float*)d_in[5];  const float* b2a = (const float*)d_in[6];
  const float* W1b = (const float*)d_in[7];  const float* b1b = (const float*)d_in[8];
  const float* W2b = (const float*)d_in[9];  const float* b2b = (const float*)d_in[10];
  const float* Wf1 = (const float*)d_in[11]; const float* bf1 = (const float*)d_in[12];
  const float* Wf2 = (const float*)d_in[13]; const float* bf2 = (const float*)d_in[14];
  const float* ln_g = (const float*)d_in[15];
  const float* ln_b = (const float*)d_in[16];

  const int N = in_sizes[0] / 128;
  const int E = in_sizes[1];
  float* out = (float*)d_out;

  size_t off = 0;
  char* wsb = (char*)d_ws;
  auto take = [&](size_t bytes) -> void* {
    void* p = wsb + off;
    off += (bytes + 255) & ~(size_t)255;
    return p;
  };
  int*   deg_s   = (int*)  take((size_t)N * 4);
  int*   deg_d   = (int*)  take((size_t)N * 4);
  float* rs_out  = (float*)take((size_t)N * 4);
  float* rs_in   = (float*)take((size_t)N * 4);
  int*   row_off = (int*)  take((size_t)(N + 1) * 4);
  int*   cursor  = (int*)  take((size_t)N * 4);
  int*   part    = (int*)  take((size_t)256 * 4);
  int*   csr_src = (int*)  take((size_t)E * 4);
  unsigned short* featb = (unsigned short*)take((size_t)N * 128 * 2);
  unsigned short* aggb  = (unsigned short*)take((size_t)N * 128 * 2);
  unsigned short* h1cat = (unsigned short*)take((size_t)N * 256 * 2);
  unsigned short* agg2  = (unsigned short*)take((size_t)N * 256 * 2);
  unsigned short* w1aT  = (unsigned short*)take(128 * 128 * 2);
  unsigned short* w1bT  = (unsigned short*)take(128 * 128 * 2);
  unsigned short* w2aT  = (unsigned short*)take(64 * 128 * 2);
  unsigned short* w2bT  = (unsigned short*)take(64 * 128 * 2);
  unsigned short* wf1T  = (unsigned short*)take(128 * 128 * 2);
  unsigned short* wf2T  = (unsigned short*)take(128 * 128 * 2);

  const int nScanBlocks = (N + 1023) / 1024;
  const int gatherBlocks = (N + 3) / 4;
  const int mtiles = (N + 63) / 64;
  const int n4 = (N * 128) / 4;

  hipMemsetAsync(deg_s, 0, (size_t)N * 4, stream);
  hipMemsetAsync(deg_d, 0, (size_t)N * 4, stream);
  count_deg<<<(E + 255) / 256, 256, 0, stream>>>(src, dst, deg_s, deg_d, E);
  make_rs<<<(N + 255) / 256, 256, 0, stream>>>(deg_s, deg_d, rs_out, rs_in, N);

  convert_feat<<<(n4 + 255) / 256, 256, 0, stream>>>(features, rs_out, featb, n4);
  convert_weights<<<6, 256, 0, stream>>>(W1a, W1b, W2a, W2b, Wf1, Wf2,
                                         w1aT, w1bT, w2aT, w2bT, wf1T, wf2T);

  scan_partial<<<nScanBlocks, 256, 0, stream>>>(deg_d, part, N);
  scan_small<<<1, 256, 0, stream>>>(part, nScanBlocks);
  scan_final<<<nScanBlocks, 256, 0, stream>>>(deg_d, part, row_off, cursor, N);
  csr_fill<<<(E + 255) / 256, 256, 0, stream>>>(src, dst, cursor, csr_src, E);

  gather128b<<<gatherBlocks, 256, 0, stream>>>(row_off, csr_src, featb, aggb, N);

  gemm1ab_mfma<<<mtiles, 256, 0, stream>>>(aggb, w1aT, b1a, w1bT, b1b,
                                           rs_in, rs_out, h1cat, N);

  gather256b<<<gatherBlocks, 256, 0, stream>>>(row_off, csr_src, h1cat, agg2, N);

  fused_tail<<<mtiles, 256, 0, stream>>>(agg2, w2aT, b2a, w2bT, b2b,
                                         features, rs_in, ln_g, ln_b,
                                         wf1T, bf1, wf2T, bf2, out, N);
}

// Round 6
// 332.754 us; speedup vs baseline: 13.0192x; 1.0304x over previous
//
#include <hip/hip_runtime.h>

#define LN_EPS 1e-5f

typedef __attribute__((ext_vector_type(8))) short bf16x8;   // 8 bf16 = 4 VGPR (MFMA A/B frag)
typedef __attribute__((ext_vector_type(4))) float f32x4;    // MFMA C/D frag

#define MFMA_B16(a, b, c) __builtin_amdgcn_mfma_f32_16x16x32_bf16((a), (b), (c), 0, 0, 0)

__device__ __forceinline__ float bflo(unsigned int u) {
  return __builtin_bit_cast(float, u << 16);
}
__device__ __forceinline__ float bfhi(unsigned int u) {
  return __builtin_bit_cast(float, u & 0xffff0000u);
}
__device__ __forceinline__ unsigned short f2bf(float f) {   // f32 -> bf16 RNE
  unsigned int u = __builtin_bit_cast(unsigned int, f);
  u += 0x7fffu + ((u >> 16) & 1u);
  return (unsigned short)(u >> 16);
}
__device__ __forceinline__ float degrs(int d) { return rsqrtf((float)max(d, 1)); }

// ---------------- degree count (both histograms, 2 atomics/edge) ----------------
__global__ __launch_bounds__(256)
void count_deg(const int* __restrict__ src, const int* __restrict__ dst,
               int* __restrict__ degs, int* __restrict__ degd, int E) {
  int t = blockIdx.x * 256 + threadIdx.x;
  if (t < E) {
    atomicAdd(&degs[src[t]], 1);
    atomicAdd(&degd[dst[t]], 1);
  }
}

// ---------------- scan: per-1024-chunk partial sums ----------------
__global__ __launch_bounds__(256)
void scan_partial(const int* __restrict__ deg, int* __restrict__ part, int N) {
  __shared__ int sd[256];
  int base = blockIdx.x * 1024;
  int t = threadIdx.x;
  int s = 0;
#pragma unroll
  for (int i = 0; i < 4; ++i) { int idx = base + t * 4 + i; if (idx < N) s += deg[idx]; }
  sd[t] = s; __syncthreads();
  for (int o = 128; o > 0; o >>= 1) { if (t < o) sd[t] += sd[t + o]; __syncthreads(); }
  if (t == 0) part[blockIdx.x] = sd[0];
}

// ---------------- scan final: inline partial-prefix, writes row_off + cursor -------
__global__ __launch_bounds__(256)
void scan_final2(const int* __restrict__ deg, const int* __restrict__ part,
                 int* __restrict__ row_off, int* __restrict__ cursor, int N) {
  __shared__ int sd[256];
  __shared__ int pex_s;
  int base = blockIdx.x * 1024;
  int t = threadIdx.x;
  if (t < 64) {                       // sum of partials before this block
    int v = 0;
    for (int i = t; i < (int)blockIdx.x; i += 64) v += part[i];
#pragma unroll
    for (int o = 1; o < 64; o <<= 1) v += __shfl_xor(v, o, 64);
    if (t == 0) pex_s = v;
  }
  int loc[4]; int s = 0;
#pragma unroll
  for (int i = 0; i < 4; ++i) {
    int idx = base + t * 4 + i;
    loc[i] = (idx < N) ? deg[idx] : 0;
    s += loc[i];
  }
  sd[t] = s; __syncthreads();
  for (int o = 1; o < 256; o <<= 1) {
    int v = (t >= o) ? sd[t - o] : 0;
    __syncthreads();
    sd[t] += v;
    __syncthreads();
  }
  int excl = sd[t] - s + pex_s;
#pragma unroll
  for (int i = 0; i < 4; ++i) {
    int idx = base + t * 4 + i;
    if (idx < N) { row_off[idx] = excl; cursor[idx] = excl; }
    excl += loc[i];
  }
  if (blockIdx.x == gridDim.x - 1 && t == 255) row_off[N] = excl;
}

// ---------------- fused: CSR fill (atomics) + feature convert + weight convert -----
// blocks [0,fillB): csr_fill ; [fillB,fillB+featB): featb = bf16(x*rs_out) ;
// [fillB+featB, +6): weight transposes. Independent work, overlapping pipes.
__global__ __launch_bounds__(256)
void fill_convert(const int* __restrict__ src, const int* __restrict__ dst,
                  int* __restrict__ cursor, int* __restrict__ csr_src, int E,
                  const float* __restrict__ x, const int* __restrict__ deg_s,
                  unsigned short* __restrict__ xb, int n4,
                  const float* __restrict__ W1a, const float* __restrict__ W1b,
                  const float* __restrict__ W2a, const float* __restrict__ W2b,
                  const float* __restrict__ Wf1, const float* __restrict__ Wf2,
                  unsigned short* __restrict__ w1aT, unsigned short* __restrict__ w1bT,
                  unsigned short* __restrict__ w2aT, unsigned short* __restrict__ w2bT,
                  unsigned short* __restrict__ wf1T, unsigned short* __restrict__ wf2T) {
  const int fillB = (E + 255) >> 8;
  const int featB = (n4 + 255) >> 8;
  int b = blockIdx.x;
  if (b < fillB) {
    int e = b * 256 + threadIdx.x;
    if (e < E) {
      int p = atomicAdd(&cursor[dst[e]], 1);
      csr_src[p] = src[e];
    }
  } else if (b < fillB + featB) {
    int t = (b - fillB) * 256 + threadIdx.x;
    if (t < n4) {
      float sc = degrs(deg_s[t >> 5]);          // 32 float4 per 128-wide row
      float4 v = reinterpret_cast<const float4*>(x)[t];
      ushort4 r;
      r.x = f2bf(v.x * sc); r.y = f2bf(v.y * sc); r.z = f2bf(v.z * sc); r.w = f2bf(v.w * sc);
      reinterpret_cast<ushort4*>(xb)[t] = r;
    }
  } else {
    const float* S; unsigned short* D; int NC;
    switch (b - fillB - featB) {
      case 0: S = W1a; D = w1aT; NC = 128; break;
      case 1: S = W1b; D = w1bT; NC = 128; break;
      case 2: S = W2a; D = w2aT; NC = 64;  break;
      case 3: S = W2b; D = w2bT; NC = 64;  break;
      case 4: S = Wf1; D = wf1T; NC = 128; break;
      default: S = Wf2; D = wf2T; NC = 128; break;
    }
    int total = 128 * NC;
    for (int i = threadIdx.x; i < total; i += 256) {
      int k = i / NC, n = i - k * NC;
      D[n * 128 + k] = f2bf(S[i]);
    }
  }
}

// ---------------- gather 128-wide: one wave/node, uint4 chunks, 4 edge slots -------
__global__ __launch_bounds__(256)
void gather128b(const int* __restrict__ row_off, const int* __restrict__ csr_src,
                const unsigned short* __restrict__ xb,
                unsigned short* __restrict__ ob, int N) {
  int n = blockIdx.x * 4 + (threadIdx.x >> 6);
  if (n >= N) return;
  int lane = threadIdx.x & 63;
  int ch = lane & 15, es = lane >> 4;        // 16B chunk, edge slot 0..3
  int beg = row_off[n], end = row_off[n + 1];
  float a[8] = {0.f, 0.f, 0.f, 0.f, 0.f, 0.f, 0.f, 0.f};
  int k = beg + es;
  for (; k + 4 < end; k += 8) {              // 8 edges per wave-iter (2 per slot)
    int s0 = csr_src[k], s1 = csr_src[k + 4];
    uint4 v0 = *reinterpret_cast<const uint4*>(xb + (size_t)s0 * 128 + ch * 8);
    uint4 v1 = *reinterpret_cast<const uint4*>(xb + (size_t)s1 * 128 + ch * 8);
    a[0] += bflo(v0.x) + bflo(v1.x); a[1] += bfhi(v0.x) + bfhi(v1.x);
    a[2] += bflo(v0.y) + bflo(v1.y); a[3] += bfhi(v0.y) + bfhi(v1.y);
    a[4] += bflo(v0.z) + bflo(v1.z); a[5] += bfhi(v0.z) + bfhi(v1.z);
    a[6] += bflo(v0.w) + bflo(v1.w); a[7] += bfhi(v0.w) + bfhi(v1.w);
  }
  if (k < end) {
    int s0 = csr_src[k];
    uint4 v0 = *reinterpret_cast<const uint4*>(xb + (size_t)s0 * 128 + ch * 8);
    a[0] += bflo(v0.x); a[1] += bfhi(v0.x);
    a[2] += bflo(v0.y); a[3] += bfhi(v0.y);
    a[4] += bflo(v0.z); a[5] += bfhi(v0.z);
    a[6] += bflo(v0.w); a[7] += bfhi(v0.w);
  }
#pragma unroll
  for (int o = 16; o < 64; o <<= 1)
#pragma unroll
    for (int i = 0; i < 8; ++i) a[i] += __shfl_xor(a[i], o, 64);
  if (es == 0) {
    uint4 r;
    r.x = (unsigned int)f2bf(a[0]) | ((unsigned int)f2bf(a[1]) << 16);
    r.y = (unsigned int)f2bf(a[2]) | ((unsigned int)f2bf(a[3]) << 16);
    r.z = (unsigned int)f2bf(a[4]) | ((unsigned int)f2bf(a[5]) << 16);
    r.w = (unsigned int)f2bf(a[6]) | ((unsigned int)f2bf(a[7]) << 16);
    *reinterpret_cast<uint4*>(ob + (size_t)n * 128 + ch * 8) = r;
  }
}

// ---------------- gather 256-wide: one wave/node, uint4 chunks, 2 edge slots -------
__global__ __launch_bounds__(256)
void gather256b(const int* __restrict__ row_off, const int* __restrict__ csr_src,
                const unsigned short* __restrict__ xb,
                unsigned short* __restrict__ ob, int N) {
  int n = blockIdx.x * 4 + (threadIdx.x >> 6);
  if (n >= N) return;
  int lane = threadIdx.x & 63;
  int ch = lane & 31, es = lane >> 5;        // 16B chunk, edge slot 0..1
  int beg = row_off[n], end = row_off[n + 1];
  float a[8] = {0.f, 0.f, 0.f, 0.f, 0.f, 0.f, 0.f, 0.f};
  int k = beg + es;
  for (; k + 2 < end; k += 4) {              // 4 edges per wave-iter (2 per slot)
    int s0 = csr_src[k], s1 = csr_src[k + 2];
    uint4 v0 = *reinterpret_cast<const uint4*>(xb + (size_t)s0 * 256 + ch * 8);
    uint4 v1 = *reinterpret_cast<const uint4*>(xb + (size_t)s1 * 256 + ch * 8);
    a[0] += bflo(v0.x) + bflo(v1.x); a[1] += bfhi(v0.x) + bfhi(v1.x);
    a[2] += bflo(v0.y) + bflo(v1.y); a[3] += bfhi(v0.y) + bfhi(v1.y);
    a[4] += bflo(v0.z) + bflo(v1.z); a[5] += bfhi(v0.z) + bfhi(v1.z);
    a[6] += bflo(v0.w) + bflo(v1.w); a[7] += bfhi(v0.w) + bfhi(v1.w);
  }
  if (k < end) {
    int s0 = csr_src[k];
    uint4 v0 = *reinterpret_cast<const uint4*>(xb + (size_t)s0 * 256 + ch * 8);
    a[0] += bflo(v0.x); a[1] += bfhi(v0.x);
    a[2] += bflo(v0.y); a[3] += bfhi(v0.y);
    a[4] += bflo(v0.z); a[5] += bfhi(v0.z);
    a[6] += bflo(v0.w); a[7] += bfhi(v0.w);
  }
#pragma unroll
  for (int i = 0; i < 8; ++i) a[i] += __shfl_xor(a[i], 32, 64);
  if (es == 0) {
    uint4 r;
    r.x = (unsigned int)f2bf(a[0]) | ((unsigned int)f2bf(a[1]) << 16);
    r.y = (unsigned int)f2bf(a[2]) | ((unsigned int)f2bf(a[3]) << 16);
    r.z = (unsigned int)f2bf(a[4]) | ((unsigned int)f2bf(a[5]) << 16);
    r.w = (unsigned int)f2bf(a[6]) | ((unsigned int)f2bf(a[7]) << 16);
    *reinterpret_cast<uint4*>(ob + (size_t)n * 256 + ch * 8) = r;
  }
}

// ---------------- gemm1 both branches, MFMA (rs inline from degrees) ---------------
// h1cat[m] = bf16( relu(rs_in[m]*(agg@[W1a|W1b]) + bias) * rs_out[m] )
__global__ __launch_bounds__(256)
void gemm1ab_mfma(const unsigned short* __restrict__ aggb,
                  const unsigned short* __restrict__ w1aT, const float* __restrict__ b1a,
                  const unsigned short* __restrict__ w1bT, const float* __restrict__ b1b,
                  const int* __restrict__ deg_s, const int* __restrict__ deg_d,
                  unsigned short* __restrict__ h1cat, int N) {
  int t = threadIdx.x, wid = t >> 6, lane = t & 63;
  int m0 = blockIdx.x * 64;
  int ll = lane & 15, lg = lane >> 4;
  int rA = m0 + wid * 16 + ll;
  const unsigned short* ap = aggb + (size_t)min(rA, N - 1) * 128 + lg * 8;
  bf16x8 A[4];
#pragma unroll
  for (int k = 0; k < 4; ++k) A[k] = *reinterpret_cast<const bf16x8*>(ap + k * 32);

  int rw0 = m0 + wid * 16 + lg * 4;
  float rsi[4], rso[4];
#pragma unroll
  for (int j = 0; j < 4; ++j) {
    int m = min(rw0 + j, N - 1);
    rsi[j] = degrs(deg_d[m]);
    rso[j] = degrs(deg_s[m]);
  }

#pragma unroll
  for (int half = 0; half < 2; ++half) {
    const unsigned short* wT = half ? w1bT : w1aT;
    const float* bias = half ? b1b : b1a;
#pragma unroll
    for (int c = 0; c < 8; ++c) {
      const unsigned short* bp = wT + (size_t)(c * 16 + ll) * 128 + lg * 8;
      f32x4 acc = {0.f, 0.f, 0.f, 0.f};
#pragma unroll
      for (int k = 0; k < 4; ++k)
        acc = MFMA_B16(A[k], *reinterpret_cast<const bf16x8*>(bp + k * 32), acc);
      int nloc = c * 16 + ll;
      int n = half * 128 + nloc;
      float bv = bias[nloc];
#pragma unroll
      for (int j = 0; j < 4; ++j) {
        int m = rw0 + j;
        if (m < N) {
          float v = fmaxf(fmaf(acc[j], rsi[j], bv), 0.f) * rso[j];
          h1cat[(size_t)m * 256 + n] = f2bf(v);
        }
      }
    }
  }
}

// ---------------- fused tail: all wave-local, zero barriers ------------------------
__global__ __launch_bounds__(256, 4)
void fused_tail(const unsigned short* __restrict__ agg2,   // [N,256] bf16
                const unsigned short* __restrict__ w2aT, const float* __restrict__ b2a,
                const unsigned short* __restrict__ w2bT, const float* __restrict__ b2b,
                const float* __restrict__ feat, const int* __restrict__ deg_d,
                const float* __restrict__ ln_g, const float* __restrict__ ln_b,
                const unsigned short* __restrict__ wf1T, const float* __restrict__ bf1,
                const unsigned short* __restrict__ wf2T, const float* __restrict__ bf2,
                float* __restrict__ out, int N) {
  __shared__ unsigned short hsb[64 * 128]; // hs bf16, XOR-swizzled; wave-private rows
  __shared__ unsigned short ffb[64 * 128]; // ffh bf16, XOR-swizzled; wave-private rows
  int t = threadIdx.x, wid = t >> 6, lane = t & 63;
  int m0 = blockIdx.x * 64;
  int ll = lane & 15, lg = lane >> 4;
  int rl0 = wid * 16 + lg * 4;             // local C-row base (this lane's 4 rows)

  // ---- phase 1: two branch GEMMs (K=128), accs in registers ----
  int rA = m0 + wid * 16 + ll;
  const unsigned short* ap = agg2 + (size_t)min(rA, N - 1) * 256 + lg * 8;
  f32x4 acc1[2][4];
#pragma unroll
  for (int br = 0; br < 2; ++br) {
    bf16x8 A[4];
#pragma unroll
    for (int k = 0; k < 4; ++k)
      A[k] = *reinterpret_cast<const bf16x8*>(ap + br * 128 + k * 32);
    const unsigned short* wT = br ? w2bT : w2aT;
#pragma unroll
    for (int c = 0; c < 4; ++c) {
      const unsigned short* bp = wT + (size_t)(c * 16 + ll) * 128 + lg * 8;
      f32x4 a = {0.f, 0.f, 0.f, 0.f};
#pragma unroll
      for (int k = 0; k < 4; ++k)
        a = MFMA_B16(A[k], *reinterpret_cast<const bf16x8*>(bp + k * 32), a);
      acc1[br][c] = a;
    }
  }

  // ---- phase 2: bias+rs, in-register LN over the 16-lane group, residual ----
  float rsv[4];
#pragma unroll
  for (int j = 0; j < 4; ++j) rsv[j] = degrs(deg_d[min(m0 + rl0 + j, N - 1)]);

  float x[8][4];                           // [col-tile ct: n=ct*16+ll][row j]; later h
  float s[4] = {0.f, 0.f, 0.f, 0.f}, q[4] = {0.f, 0.f, 0.f, 0.f};
#pragma unroll
  for (int br = 0; br < 2; ++br) {
    const float* bias = br ? b2b : b2a;
#pragma unroll
    for (int c = 0; c < 4; ++c) {
      float bv = bias[c * 16 + ll];
#pragma unroll
      for (int j = 0; j < 4; ++j) {
        float v = fmaf(acc1[br][c][j], rsv[j], bv);
        x[br * 4 + c][j] = v;
        s[j] += v;
        q[j] += v * v;
      }
    }
  }
#pragma unroll
  for (int o = 1; o < 16; o <<= 1) {
#pragma unroll
    for (int j = 0; j < 4; ++j) {
      s[j] += __shfl_xor(s[j], o, 64);
      q[j] += __shfl_xor(q[j], o, 64);
    }
  }
  float mu[4], rstd[4];
#pragma unroll
  for (int j = 0; j < 4; ++j) {
    mu[j] = s[j] * (1.f / 128.f);
    float var = fmaxf(q[j] * (1.f / 128.f) - mu[j] * mu[j], 0.f);
    rstd[j] = rsqrtf(var + LN_EPS);
  }
#pragma unroll
  for (int ct = 0; ct < 8; ++ct) {
    int n = ct * 16 + ll;
    float gv = ln_g[n], bv = ln_b[n];
#pragma unroll
    for (int j = 0; j < 4; ++j) {
      int m = min(m0 + rl0 + j, N - 1);
      float hv = feat[(size_t)m * 128 + n] + (x[ct][j] - mu[j]) * rstd[j] * gv + bv;
      x[ct][j] = hv;                                     // keep f32 h for residual
      int r = rl0 + j;
      hsb[r * 128 + (n ^ ((r & 7) << 3))] = f2bf(hv);    // swizzled bf16 for FFN1
    }
  }
  // no barrier: each wave reads only rows it wrote

  // ---- phase 3: FFN1 = relu(hs @ Wf1 + bf1) -> ffb ----
  {
    int rloc = wid * 16 + ll;
    int swr = (rloc & 7) << 3;
    bf16x8 A[4];
#pragma unroll
    for (int k = 0; k < 4; ++k)
      A[k] = *reinterpret_cast<const bf16x8*>(hsb + rloc * 128 + ((lg * 8 + k * 32) ^ swr));
#pragma unroll
    for (int c = 0; c < 8; ++c) {
      const unsigned short* bp = wf1T + (size_t)(c * 16 + ll) * 128 + lg * 8;
      f32x4 a = {0.f, 0.f, 0.f, 0.f};
#pragma unroll
      for (int k = 0; k < 4; ++k)
        a = MFMA_B16(A[k], *reinterpret_cast<const bf16x8*>(bp + k * 32), a);
      int n = c * 16 + ll;
      float bv = bf1[n];
#pragma unroll
      for (int j = 0; j < 4; ++j) {
        int r = rl0 + j;
        ffb[r * 128 + (n ^ ((r & 7) << 3))] = f2bf(fmaxf(a[j] + bv, 0.f));
      }
    }
  }

  // ---- phase 4: FFN2 + residual -> out ----
  {
    int rloc = wid * 16 + ll;
    int swr = (rloc & 7) << 3;
    bf16x8 A[4];
#pragma unroll
    for (int k = 0; k < 4; ++k)
      A[k] = *reinterpret_cast<const bf16x8*>(ffb + rloc * 128 + ((lg * 8 + k * 32) ^ swr));
#pragma unroll
    for (int c = 0; c < 8; ++c) {
      const unsigned short* bp = wf2T + (size_t)(c * 16 + ll) * 128 + lg * 8;
      f32x4 a = {0.f, 0.f, 0.f, 0.f};
#pragma unroll
      for (int k = 0; k < 4; ++k)
        a = MFMA_B16(A[k], *reinterpret_cast<const bf16x8*>(bp + k * 32), a);
      int n = c * 16 + ll;
      float bv = bf2[n];
#pragma unroll
      for (int j = 0; j < 4; ++j) {
        int m = m0 + rl0 + j;
        if (m < N) out[(size_t)m * 128 + n] = x[c][j] + a[j] + bv;
      }
    }
  }
}

extern "C" void kernel_launch(void* const* d_in, const int* in_sizes, int n_in,
                              void* d_out, int out_size, void* d_ws, size_t ws_size,
                              hipStream_t stream) {
  const float* features = (const float*)d_in[0];
  const int*   src      = (const int*)d_in[1];
  const int*   dst      = (const int*)d_in[2];
  const float* W1a = (const float*)d_in[3];  const float* b1a = (const float*)d_in[4];
  const float* W2a = (const float*)d_in[5];  const float* b2a = (const float*)d_in[6];
  const float* W1b = (const float*)d_in[7];  const float* b1b = (const float*)d_in[8];
  const float* W2b = (const float*)d_in[9];  const float* b2b = (const float*)d_in[10];
  const float* Wf1 = (const float*)d_in[11]; const float* bf1 = (const float*)d_in[12];
  const float* Wf2 = (const float*)d_in[13]; const float* bf2 = (const float*)d_in[14];
  const float* ln_g = (const float*)d_in[15];
  const float* ln_b = (const float*)d_in[16];

  const int N = in_sizes[0] / 128;
  const int E = in_sizes[1];
  float* out = (float*)d_out;

  size_t off = 0;
  char* wsb = (char*)d_ws;
  auto take = [&](size_t bytes) -> void* {
    void* p = wsb + off;
    off += (bytes + 255) & ~(size_t)255;
    return p;
  };
  int*   degs2   = (int*)  take((size_t)2 * N * 4);   // deg_s | deg_d (one memset)
  int*   deg_s   = degs2;
  int*   deg_d   = degs2 + N;
  int*   row_off = (int*)  take((size_t)(N + 1) * 4);
  int*   cursor  = (int*)  take((size_t)N * 4);
  int*   part    = (int*)  take((size_t)256 * 4);
  int*   csr_src = (int*)  take((size_t)E * 4);
  unsigned short* featb = (unsigned short*)take((size_t)N * 128 * 2);
  unsigned short* aggb  = (unsigned short*)take((size_t)N * 128 * 2);
  unsigned short* h1cat = (unsigned short*)take((size_t)N * 256 * 2);
  unsigned short* agg2  = (unsigned short*)take((size_t)N * 256 * 2);
  unsigned short* w1aT  = (unsigned short*)take(128 * 128 * 2);
  unsigned short* w1bT  = (unsigned short*)take(128 * 128 * 2);
  unsigned short* w2aT  = (unsigned short*)take(64 * 128 * 2);
  unsigned short* w2bT  = (unsigned short*)take(64 * 128 * 2);
  unsigned short* wf1T  = (unsigned short*)take(128 * 128 * 2);
  unsigned short* wf2T  = (unsigned short*)take(128 * 128 * 2);

  const int nScanBlocks = (N + 1023) / 1024;
  const int gatherBlocks = (N + 3) / 4;
  const int mtiles = (N + 63) / 64;
  const int n4 = (N * 128) / 4;
  const int fillB = (E + 255) / 256;
  const int featB = (n4 + 255) / 256;

  // 1) zero both degree arrays (adjacent)
  hipMemsetAsync(degs2, 0, (size_t)2 * N * 4, stream);
  // 2) degree histograms
  count_deg<<<(E + 255) / 256, 256, 0, stream>>>(src, dst, deg_s, deg_d, E);
  // 3-4) scan deg_d -> row_off + cursor
  scan_partial<<<nScanBlocks, 256, 0, stream>>>(deg_d, part, N);
  scan_final2<<<nScanBlocks, 256, 0, stream>>>(deg_d, part, row_off, cursor, N);
  // 5) CSR fill (atomics) + feature/weight converts, overlapped in one dispatch
  fill_convert<<<fillB + featB + 6, 256, 0, stream>>>(
      src, dst, cursor, csr_src, E,
      features, deg_s, featb, n4,
      W1a, W1b, W2a, W2b, Wf1, Wf2,
      w1aT, w1bT, w2aT, w2bT, wf1T, wf2T);
  // 6) first aggregation
  gather128b<<<gatherBlocks, 256, 0, stream>>>(row_off, csr_src, featb, aggb, N);
  // 7) h1cat = relu(rs_in*(agg@[W1a|W1b]) + bias) * rs_out
  gemm1ab_mfma<<<mtiles, 256, 0, stream>>>(aggb, w1aT, b1a, w1bT, b1b,
                                           deg_s, deg_d, h1cat, N);
  // 8) second aggregation (both branches)
  gather256b<<<gatherBlocks, 256, 0, stream>>>(row_off, csr_src, h1cat, agg2, N);
  // 9) fused MFMA tail
  fused_tail<<<mtiles, 256, 0, stream>>>(agg2, w2aT, b2a, w2bT, b2b,
                                         features, deg_d, ln_g, ln_b,
                                         wf1T, bf1, wf2T, bf2, out, N);
}